// Round 5
// baseline (165.754 us; speedup 1.0000x reference)
//
#include <hip/hip_runtime.h>

typedef __attribute__((ext_vector_type(8))) short bf16x8;
typedef __attribute__((ext_vector_type(4))) float f32x4;
typedef __attribute__((ext_vector_type(4))) unsigned short u16x4;
typedef unsigned short u16;
typedef unsigned int u32;

static __device__ __forceinline__ u16 f2bf(float f) {
  u32 u = __float_as_uint(f);
  u32 r = (u + 0x7fffu + ((u >> 16) & 1u)) >> 16;  // RNE
  return (u16)r;
}

static __device__ __forceinline__ u32 cvt_pk(float lo, float hi) {
  u32 r;
  asm("v_cvt_pk_bf16_f32 %0, %1, %2" : "=v"(r) : "v"(lo), "v"(hi));
  return r;
}

#define GLDS16(g, l)                                                        \
  __builtin_amdgcn_global_load_lds(                                         \
      (const __attribute__((address_space(1))) u32*)(g),                    \
      (__attribute__((address_space(3))) u32*)(l), 16, 0, 0)

#define SC2F 0.18033688011112042f  // 0.125 * log2(e)

// ---------------- cast kernels ----------------
__global__ __launch_bounds__(256) void cast_x(const float* __restrict__ x,
                                              u16* __restrict__ xb) {
  int i = blockIdx.x * 256 + threadIdx.x;  // one thread per 8 elems
  const float4* xv = (const float4*)x;
  float4 a = xv[i * 2], b = xv[i * 2 + 1];
  bf16x8 o;
  o[0] = f2bf(a.x); o[1] = f2bf(a.y); o[2] = f2bf(a.z); o[3] = f2bf(a.w);
  o[4] = f2bf(b.x); o[5] = f2bf(b.y); o[6] = f2bf(b.z); o[7] = f2bf(b.w);
  *(bf16x8*)(xb + i * 8) = o;
}

// Wqkv_t[n][d], n = sel*1024 + h*64 + kk; value = W_sel[h][d][kk]
__global__ __launch_bounds__(256) void cast_wqkv(const float* __restrict__ wq,
                                                 const float* __restrict__ wk,
                                                 const float* __restrict__ wv,
                                                 u16* __restrict__ wt) {
  int tid = blockIdx.x * 256 + threadIdx.x;  // 3M
  int n = tid >> 10, d = tid & 1023;
  int sel = n >> 10, r = n & 1023, h = r >> 6, kk = r & 63;
  const float* src = sel == 0 ? wq : (sel == 1 ? wk : wv);
  wt[tid] = f2bf(src[h * 65536 + d * 64 + kk]);
}

// WOt[n][k] = W_O[k][n]
__global__ __launch_bounds__(256) void cast_wo(const float* __restrict__ wo,
                                               u16* __restrict__ wt) {
  int tid = blockIdx.x * 256 + threadIdx.x;  // 1M
  int n = tid >> 10, k = tid & 1023;
  wt[tid] = f2bf(wo[k * 1024 + n]);
}

// ---------------- GEMM: C = A(bf16)[M,K] * Bt(bf16)[N,K]^T ----------------
// 2-phase double-buffered staging, XCD-swizzled grid (nwg % 8 == 0).
// MODE 1: float C [M,N].  MODE 2: col<1024 -> Q*SC2F bf16; col<2048 -> K bf16;
//          col>=2048 -> Vt[(b*1024 + (col-2048))*2048 + s], row = b*2048+s.
template <int MODE>
__global__ __launch_bounds__(256) void gemm_bt(const u16* __restrict__ A,
                                               const u16* __restrict__ Bt,
                                               void* __restrict__ Cp,
                                               u16* __restrict__ Vt, int M,
                                               int N, int K) {
  const int t = threadIdx.x;
  const int lane = t & 63, w = t >> 6;
  const int lr = lane & 15, lg = lane >> 4;
  const int wr = w >> 1, wc = w & 1;
  // XCD-aware swizzle: contiguous tile chunk per XCD (T1)
  int lin = blockIdx.y * gridDim.x + blockIdx.x;
  int nwg = gridDim.x * gridDim.y;
  int swz = (lin & 7) * (nwg >> 3) + (lin >> 3);
  int bx = swz % gridDim.x, by = swz / gridDim.x;
  const int m0 = by * 128, n0 = bx * 128;
  __shared__ __align__(16) u16 As[2][128 * 32];
  __shared__ __align__(16) u16 Bs[2][128 * 32];
  const int r0 = t >> 2, cb = (t & 3) * 8;
  const u16* a0 = A + (size_t)(m0 + r0) * K + cb;
  const u16* b0 = Bt + (size_t)(n0 + r0) * K + cb;
  const size_t rowjmp = (size_t)64 * K;
  f32x4 acc[4][4] = {};

#define GSTAGE(bb, k0)                                      \
  {                                                         \
    GLDS16(a0 + (k0), &As[bb][t * 8]);                      \
    GLDS16(a0 + rowjmp + (k0), &As[bb][2048 + t * 8]);      \
    GLDS16(b0 + (k0), &Bs[bb][t * 8]);                      \
    GLDS16(b0 + rowjmp + (k0), &Bs[bb][2048 + t * 8]);      \
  }

  GSTAGE(0, 0);
  __syncthreads();
  for (int k0 = 0; k0 < K; k0 += 32) {
    const int bb = (k0 >> 5) & 1;
    if (k0 + 32 < K) GSTAGE(bb ^ 1, k0 + 32);
    bf16x8 a[4], b[4];
#pragma unroll
    for (int m = 0; m < 4; ++m)
      a[m] = *(const bf16x8*)&As[bb][(wr * 64 + m * 16 + lr) * 32 + lg * 8];
#pragma unroll
    for (int n = 0; n < 4; ++n)
      b[n] = *(const bf16x8*)&Bs[bb][(wc * 64 + n * 16 + lr) * 32 + lg * 8];
    __builtin_amdgcn_s_setprio(1);
#pragma unroll
    for (int m = 0; m < 4; ++m)
#pragma unroll
      for (int n = 0; n < 4; ++n)
        acc[m][n] =
            __builtin_amdgcn_mfma_f32_16x16x32_bf16(a[m], b[n], acc[m][n], 0, 0, 0);
    __builtin_amdgcn_s_setprio(0);
    __syncthreads();
  }
#undef GSTAGE

#pragma unroll
  for (int m = 0; m < 4; ++m) {
    int rowg = m0 + wr * 64 + m * 16 + lg * 4;
#pragma unroll
    for (int n = 0; n < 4; ++n) {
      int colg = n0 + wc * 64 + n * 16 + lr;
      if (MODE == 1) {
        float* C = (float*)Cp;
#pragma unroll
        for (int j = 0; j < 4; ++j)
          C[(size_t)(rowg + j) * N + colg] = acc[m][n][j];
      } else {
        if (colg < 1024) {  // Q: fold softmax scale (exp2 domain)
          u16* C = (u16*)Cp;
#pragma unroll
          for (int j = 0; j < 4; ++j)
            C[(size_t)(rowg + j) * 2048 + colg] = f2bf(acc[m][n][j] * SC2F);
        } else if (colg < 2048) {  // K
          u16* C = (u16*)Cp;
#pragma unroll
          for (int j = 0; j < 4; ++j)
            C[(size_t)(rowg + j) * 2048 + colg] = f2bf(acc[m][n][j]);
        } else {  // V, stored transposed [dk_total][S]
          int vidx = colg - 2048, bb2 = rowg >> 11, s = rowg & 2047;
          u16x4 pk;
#pragma unroll
          for (int j = 0; j < 4; ++j) pk[j] = f2bf(acc[m][n][j]);
          *(u16x4*)(Vt + (size_t)(bb2 * 1024 + vidx) * 2048 + s) = pk;
        }
      }
    }
  }
}

// ---------------- flash attention (swapped QK^T, T15 pipelined PV) --------
// grid: 1024 blocks = (b,h) * 32 q-tiles of 64 rows; 4 waves * 16 q-rows.
// Iter t: PV(t-1) pure-register MFMA (paP/vfP read last iter) -> stage(t+1)
// -> QK(t) -> vf(t) reads -> softmax(t) -> pack(t) -> paP reads -> barrier.
// LDS = 16K Kdbuf + 16K Vdbuf + 8K Ps = 40960 B => 4 blocks/CU.
__global__ __launch_bounds__(256) void attn(const u16* __restrict__ qkb,
                                            const u16* __restrict__ vtb,
                                            u16* __restrict__ hb) {
  const int t = threadIdx.x, lane = t & 63, w = t >> 6;
  const int lr = lane & 15, lg = lane >> 4;
  // XCD swizzle: 128 consecutive tiles (4 (b,h) groups => 2MB K/V) per XCD
  int lin = blockIdx.x;
  int swz2 = (lin & 7) * 128 + (lin >> 3);
  int qi = swz2 & 31, bh = swz2 >> 5;
  int b = bh >> 4, h = bh & 15;
  int q0 = qi * 64;
  __shared__ __align__(16) u16 Ks[2][64 * 64];   // [s][dk], chunk^=(s&7)
  __shared__ __align__(16) u16 Vts[2][64 * 64];  // [dk][s], chunk^=(d&7)
  __shared__ __align__(16) u32 Ps[4][16 * 32];   // per-wave packed P, swizzled

  const u16* qbase = qkb + (size_t)(b * 2048 + q0 + w * 16 + lr) * 2048 + h * 64;
  bf16x8 qf0 = *(const bf16x8*)(qbase + lg * 8);
  bf16x8 qf1 = *(const bf16x8*)(qbase + 32 + lg * 8);

  f32x4 oacc[4] = {};
  float mrun = -1e30f, lrun = 0.f;
  bf16x8 paP[2] = {};      // P fragments of previous tile (zero => no-op PV)
  bf16x8 vfP[2][4] = {};   // V fragments of previous tile

  int off[2][4];
#pragma unroll
  for (int kk = 0; kk < 2; ++kk)
#pragma unroll
    for (int n = 0; n < 4; ++n) {
      int s = n * 16 + lr;
      off[kk][n] = s * 64 + (((kk * 4 + lg) ^ (s & 7)) * 8);
    }
  const int xw = (lr & 7) << 2;  // Ps word-swizzle

  const int rr = t >> 3, cbb = t & 7;
  const int swz = (cbb ^ (rr & 7)) * 8;
  const u16* Kg = qkb + (size_t)(b * 2048) * 2048 + 1024 + h * 64;
  const u16* Vg = vtb + (size_t)(b * 1024 + h * 64) * 2048;
  const u16* kp0 = Kg + (size_t)rr * 2048 + swz;
  const u16* vp0 = Vg + (size_t)rr * 2048 + swz;
  u32* Pw = &Ps[w][0];

#define ASTAGE(bb, tv)                                   \
  {                                                      \
    const u16* kp = kp0 + (size_t)(tv)*131072;           \
    const u16* vp = vp0 + (tv)*64;                       \
    GLDS16(kp, &Ks[bb][t * 8]);                          \
    GLDS16(kp + 65536, &Ks[bb][2048 + t * 8]);           \
    GLDS16(vp, &Vts[bb][t * 8]);                         \
    GLDS16(vp + 65536, &Vts[bb][2048 + t * 8]);          \
  }

  ASTAGE(0, 0);
  __syncthreads();

  for (int tv = 0; tv < 32; ++tv) {
    const int bb = tv & 1;

    // PV(t-1): pure-register MFMAs — fill matrix pipe, no waits
    __builtin_amdgcn_s_setprio(1);
#pragma unroll
    for (int kk = 0; kk < 2; ++kk)
#pragma unroll
      for (int n = 0; n < 4; ++n)
        oacc[n] =
            __builtin_amdgcn_mfma_f32_16x16x32_bf16(paP[kk], vfP[kk][n], oacc[n], 0, 0, 0);

    if (tv < 31) ASTAGE(bb ^ 1, tv + 1);  // issue early, lands by barrier

    // QK(t): S^T = K * Q^T; lane holds S[q=lr][k=16n+4lg+j]
    f32x4 sacc[4] = {};
#pragma unroll
    for (int kk = 0; kk < 2; ++kk) {
      bf16x8 qf = kk ? qf1 : qf0;
#pragma unroll
      for (int n = 0; n < 4; ++n) {
        bf16x8 kf = *(const bf16x8*)&Ks[bb][off[kk][n]];
        sacc[n] = __builtin_amdgcn_mfma_f32_16x16x32_bf16(kf, qf, sacc[n], 0, 0, 0);
      }
    }
    __builtin_amdgcn_s_setprio(0);

    // V fragments of tile t -> registers (used next iteration)
#pragma unroll
    for (int kk = 0; kk < 2; ++kk)
#pragma unroll
      for (int n = 0; n < 4; ++n)
        vfP[kk][n] = *(const bf16x8*)&Vts[bb][off[kk][n]];

    // softmax(t): per-lane scalar state (scale pre-folded into Q)
    float t0 = fmaxf(fmaxf(sacc[0][0], sacc[0][1]), sacc[0][2]);
    float t1 = fmaxf(fmaxf(sacc[0][3], sacc[1][0]), sacc[1][1]);
    float t2 = fmaxf(fmaxf(sacc[1][2], sacc[1][3]), sacc[2][0]);
    float t3 = fmaxf(fmaxf(sacc[2][1], sacc[2][2]), sacc[2][3]);
    float t4 = fmaxf(fmaxf(sacc[3][0], sacc[3][1]), sacc[3][2]);
    float pm = fmaxf(fmaxf(fmaxf(t0, t1), fmaxf(t2, t3)), fmaxf(t4, sacc[3][3]));
    pm = fmaxf(pm, __shfl_xor(pm, 16));
    pm = fmaxf(pm, __shfl_xor(pm, 32));

    if (__any(pm > mrun + 8.0f)) {  // T13 defer-max (rare after tile 0)
      float mnew = fmaxf(mrun, pm);
      float al = __builtin_amdgcn_exp2f(mrun - mnew);
      lrun *= al;
      float alj[4];
#pragma unroll
      for (int j = 0; j < 4; ++j) alj[j] = __shfl(al, 4 * lg + j);
#pragma unroll
      for (int n = 0; n < 4; ++n)
#pragma unroll
        for (int j = 0; j < 4; ++j) oacc[n][j] *= alj[j];
      mrun = mnew;
    }

    // fused exp + rowsum + pack (no p[] array)
    float ps = 0.f;
#pragma unroll
    for (int n = 0; n < 4; ++n) {
      float v0 = __builtin_amdgcn_exp2f(sacc[n][0] - mrun);
      float v1 = __builtin_amdgcn_exp2f(sacc[n][1] - mrun);
      float v2 = __builtin_amdgcn_exp2f(sacc[n][2] - mrun);
      float v3 = __builtin_amdgcn_exp2f(sacc[n][3] - mrun);
      ps += (v0 + v1) + (v2 + v3);
      Pw[lr * 32 + ((8 * n + 2 * lg) ^ xw)] = cvt_pk(v0, v1);
      Pw[lr * 32 + ((8 * n + 2 * lg + 1) ^ xw)] = cvt_pk(v2, v3);
    }
    ps += __shfl_xor(ps, 16);
    ps += __shfl_xor(ps, 32);
    lrun += ps;

    // P fragments of tile t -> registers (same-wave DS in-order after writes)
#pragma unroll
    for (int kk = 0; kk < 2; ++kk)
      paP[kk] = *(const bf16x8*)&Pw[lr * 32 + ((16 * kk + 4 * lg) ^ xw)];

    __syncthreads();
  }
#undef ASTAGE

  // epilogue: PV(31)
  __builtin_amdgcn_s_setprio(1);
#pragma unroll
  for (int kk = 0; kk < 2; ++kk)
#pragma unroll
    for (int n = 0; n < 4; ++n)
      oacc[n] =
          __builtin_amdgcn_mfma_f32_16x16x32_bf16(paP[kk], vfP[kk][n], oacc[n], 0, 0, 0);
  __builtin_amdgcn_s_setprio(0);

  float rinv = __builtin_amdgcn_rcpf(lrun);
  float rj[4];
#pragma unroll
  for (int j = 0; j < 4; ++j) rj[j] = __shfl(rinv, 4 * lg + j);
  int rowg = b * 2048 + q0 + w * 16 + lg * 4;
#pragma unroll
  for (int n = 0; n < 4; ++n) {
    int col = h * 64 + n * 16 + lr;
#pragma unroll
    for (int j = 0; j < 4; ++j)
      hb[(size_t)(rowg + j) * 1024 + col] = f2bf(oacc[n][j] * rj[j]);
  }
}

extern "C" void kernel_launch(void* const* d_in, const int* in_sizes, int n_in,
                              void* d_out, int out_size, void* d_ws,
                              size_t ws_size, hipStream_t stream) {
  const float* x = (const float*)d_in[0];
  const float* wq = (const float*)d_in[1];
  const float* wk = (const float*)d_in[2];
  const float* wv = (const float*)d_in[3];
  const float* wo = (const float*)d_in[4];

  u16* xb = (u16*)d_ws;              // [4096][1024]        4M
  u16* wqkv = xb + 4 * 1024 * 1024;  // [3072][1024]        3M
  u16* wot = wqkv + 3 * 1024 * 1024; // [1024][1024]        1M
  u16* qkb = wot + 1024 * 1024;      // [4096][2048] Q|K    8M
  u16* vtb = qkb + 8 * 1024 * 1024;  // [2][1024][2048] Vt  4M
  u16* hb = vtb + 4 * 1024 * 1024;   // [4096][1024] heads  4M

  cast_x<<<2048, 256, 0, stream>>>(x, xb);
  cast_wqkv<<<12288, 256, 0, stream>>>(wq, wk, wv, wqkv);
  cast_wo<<<4096, 256, 0, stream>>>(wo, wot);
  gemm_bt<2><<<dim3(24, 32), 256, 0, stream>>>(xb, wqkv, qkb, vtb, 4096, 3072, 1024);
  attn<<<1024, 256, 0, stream>>>(qkb, vtb, hb);
  gemm_bt<1><<<dim3(8, 32), 256, 0, stream>>>(hb, wot, d_out, nullptr, 4096, 1024, 1024);
}

// Round 6
// 152.689 us; speedup vs baseline: 1.0856x; 1.0856x over previous
//
#include <hip/hip_runtime.h>

typedef __attribute__((ext_vector_type(8))) short bf16x8;
typedef __attribute__((ext_vector_type(4))) float f32x4;
typedef __attribute__((ext_vector_type(4))) unsigned short u16x4;
typedef unsigned short u16;
typedef unsigned int u32;

static __device__ __forceinline__ u16 f2bf(float f) {
  u32 u = __float_as_uint(f);
  u32 r = (u + 0x7fffu + ((u >> 16) & 1u)) >> 16;  // RNE
  return (u16)r;
}

static __device__ __forceinline__ u32 cvt_pk(float lo, float hi) {
  u32 r;
  asm("v_cvt_pk_bf16_f32 %0, %1, %2" : "=v"(r) : "v"(lo), "v"(hi));
  return r;
}

#define GLDS16(g, l)                                                        \
  __builtin_amdgcn_global_load_lds(                                         \
      (const __attribute__((address_space(1))) u32*)(g),                    \
      (__attribute__((address_space(3))) u32*)(l), 16, 0, 0)

#define WAIT_VM4() asm volatile("s_waitcnt vmcnt(4)" ::: "memory")
#define WAIT_VM0() asm volatile("s_waitcnt vmcnt(0)" ::: "memory")
#define RAWBAR() __builtin_amdgcn_s_barrier()

#define SC2F 0.18033688011112042f  // 0.125 * log2(e)

// ---------------- cast kernels ----------------
__global__ __launch_bounds__(256) void cast_x(const float* __restrict__ x,
                                              u16* __restrict__ xb) {
  int i = blockIdx.x * 256 + threadIdx.x;  // one thread per 8 elems
  const float4* xv = (const float4*)x;
  float4 a = xv[i * 2], b = xv[i * 2 + 1];
  bf16x8 o;
  o[0] = f2bf(a.x); o[1] = f2bf(a.y); o[2] = f2bf(a.z); o[3] = f2bf(a.w);
  o[4] = f2bf(b.x); o[5] = f2bf(b.y); o[6] = f2bf(b.z); o[7] = f2bf(b.w);
  *(bf16x8*)(xb + i * 8) = o;
}

// Wqkv_t[n][d], n = sel*1024 + h*64 + kk; value = W_sel[h][d][kk]
__global__ __launch_bounds__(256) void cast_wqkv(const float* __restrict__ wq,
                                                 const float* __restrict__ wk,
                                                 const float* __restrict__ wv,
                                                 u16* __restrict__ wt) {
  int tid = blockIdx.x * 256 + threadIdx.x;  // 3M
  int n = tid >> 10, d = tid & 1023;
  int sel = n >> 10, r = n & 1023, h = r >> 6, kk = r & 63;
  const float* src = sel == 0 ? wq : (sel == 1 ? wk : wv);
  wt[tid] = f2bf(src[h * 65536 + d * 64 + kk]);
}

// WOt[n][k] = W_O[k][n]
__global__ __launch_bounds__(256) void cast_wo(const float* __restrict__ wo,
                                               u16* __restrict__ wt) {
  int tid = blockIdx.x * 256 + threadIdx.x;  // 1M
  int n = tid >> 10, k = tid & 1023;
  wt[tid] = f2bf(wo[k * 1024 + n]);
}

// ---------------- GEMM: C = A(bf16)[M,K] * Bt(bf16)[N,K]^T ----------------
// dbuf staging + RAW barriers + counted vmcnt(4): next tile's loads stay in
// flight across the barrier (T4); XCD-swizzled grid (nwg % 8 == 0).
// MODE 1: float C [M,N].  MODE 2: col<1024 -> Q*SC2F bf16; col<2048 -> K bf16;
//          col>=2048 -> Vt[(b*1024 + (col-2048))*2048 + s], row = b*2048+s.
template <int MODE>
__global__ __launch_bounds__(256) void gemm_bt(const u16* __restrict__ A,
                                               const u16* __restrict__ Bt,
                                               void* __restrict__ Cp,
                                               u16* __restrict__ Vt, int M,
                                               int N, int K) {
  const int t = threadIdx.x;
  const int lane = t & 63, w = t >> 6;
  const int lr = lane & 15, lg = lane >> 4;
  const int wr = w >> 1, wc = w & 1;
  // XCD-aware swizzle: contiguous tile chunk per XCD (T1)
  int lin = blockIdx.y * gridDim.x + blockIdx.x;
  int nwg = gridDim.x * gridDim.y;
  int swz = (lin & 7) * (nwg >> 3) + (lin >> 3);
  int bx = swz % gridDim.x, by = swz / gridDim.x;
  const int m0 = by * 128, n0 = bx * 128;
  __shared__ __align__(16) u16 As[2][128 * 32];
  __shared__ __align__(16) u16 Bs[2][128 * 32];
  const int r0 = t >> 2, cb = (t & 3) * 8;
  const u16* a0 = A + (size_t)(m0 + r0) * K + cb;
  const u16* b0 = Bt + (size_t)(n0 + r0) * K + cb;
  const size_t rowjmp = (size_t)64 * K;
  f32x4 acc[4][4] = {};

#define GSTAGE(bb, k0)                                      \
  {                                                         \
    GLDS16(a0 + (k0), &As[bb][t * 8]);                      \
    GLDS16(a0 + rowjmp + (k0), &As[bb][2048 + t * 8]);      \
    GLDS16(b0 + (k0), &Bs[bb][t * 8]);                      \
    GLDS16(b0 + rowjmp + (k0), &Bs[bb][2048 + t * 8]);      \
  }

  GSTAGE(0, 0);
  for (int k0 = 0; k0 < K; k0 += 32) {
    const int bb = (k0 >> 5) & 1;
    if (k0 + 32 < K) {
      GSTAGE(bb ^ 1, k0 + 32);  // issue next tile first
      WAIT_VM4();               // only THIS tile's loads must have landed
    } else {
      WAIT_VM0();
    }
    RAWBAR();  // all waves' current-tile loads landed
    bf16x8 a[4], b[4];
#pragma unroll
    for (int m = 0; m < 4; ++m)
      a[m] = *(const bf16x8*)&As[bb][(wr * 64 + m * 16 + lr) * 32 + lg * 8];
#pragma unroll
    for (int n = 0; n < 4; ++n)
      b[n] = *(const bf16x8*)&Bs[bb][(wc * 64 + n * 16 + lr) * 32 + lg * 8];
    __builtin_amdgcn_s_setprio(1);
#pragma unroll
    for (int m = 0; m < 4; ++m)
#pragma unroll
      for (int n = 0; n < 4; ++n)
        acc[m][n] =
            __builtin_amdgcn_mfma_f32_16x16x32_bf16(a[m], b[n], acc[m][n], 0, 0, 0);
    __builtin_amdgcn_s_setprio(0);
    RAWBAR();  // bounds wave skew; no vmcnt drain (frags already consumed)
  }
#undef GSTAGE

#pragma unroll
  for (int m = 0; m < 4; ++m) {
    int rowg = m0 + wr * 64 + m * 16 + lg * 4;
#pragma unroll
    for (int n = 0; n < 4; ++n) {
      int colg = n0 + wc * 64 + n * 16 + lr;
      if (MODE == 1) {
        float* C = (float*)Cp;
#pragma unroll
        for (int j = 0; j < 4; ++j)
          C[(size_t)(rowg + j) * N + colg] = acc[m][n][j];
      } else {
        if (colg < 1024) {  // Q: fold softmax scale (exp2 domain)
          u16* C = (u16*)Cp;
#pragma unroll
          for (int j = 0; j < 4; ++j)
            C[(size_t)(rowg + j) * 2048 + colg] = f2bf(acc[m][n][j] * SC2F);
        } else if (colg < 2048) {  // K
          u16* C = (u16*)Cp;
#pragma unroll
          for (int j = 0; j < 4; ++j)
            C[(size_t)(rowg + j) * 2048 + colg] = f2bf(acc[m][n][j]);
        } else {  // V, stored transposed [dk_total][S]
          int vidx = colg - 2048, bb2 = rowg >> 11, s = rowg & 2047;
          u16x4 pk;
#pragma unroll
          for (int j = 0; j < 4; ++j) pk[j] = f2bf(acc[m][n][j]);
          *(u16x4*)(Vt + (size_t)(bb2 * 1024 + vidx) * 2048 + s) = pk;
        }
      }
    }
  }
}

// ---------------- flash attention (swapped QK^T, counted-vmcnt dbuf) ------
// grid: 1024 blocks = (b,h) * 32 q-tiles of 64 rows; 4 waves * 16 q-rows.
// sacc = mfma(K_frag, Q_frag) => lane holds S[q=lr][k=16n+4lg+j];
// softmax state (m,l) per-lane scalar. Q pre-scaled by SC2F in GEMM.
// Raw barriers + vmcnt(4): next KV tile's 4 GLDS stay in flight across bar.
// LDS = 16K Kdbuf + 16K Vdbuf + 8K Ps = 40960 B => 4 blocks/CU.
__global__ __launch_bounds__(256) void attn(const u16* __restrict__ qkb,
                                            const u16* __restrict__ vtb,
                                            u16* __restrict__ hb) {
  const int t = threadIdx.x, lane = t & 63, w = t >> 6;
  const int lr = lane & 15, lg = lane >> 4;
  int blk = blockIdx.x;
  int qi = blk & 31, bh = blk >> 5;
  int b = bh >> 4, h = bh & 15;
  int q0 = qi * 64;
  __shared__ __align__(16) u16 Ks[2][64 * 64];   // [s][dk], chunk^=(s&7)
  __shared__ __align__(16) u16 Vts[2][64 * 64];  // [dk][s], chunk^=(d&7)
  __shared__ __align__(16) u32 Ps[4][16 * 32];   // per-wave packed P, swizzled

  const u16* qbase = qkb + (size_t)(b * 2048 + q0 + w * 16 + lr) * 2048 + h * 64;
  bf16x8 qf0 = *(const bf16x8*)(qbase + lg * 8);
  bf16x8 qf1 = *(const bf16x8*)(qbase + 32 + lg * 8);

  f32x4 oacc[4] = {};
  float mrun = -1e30f, lrun = 0.f;

  int off[2][4];
#pragma unroll
  for (int kk = 0; kk < 2; ++kk)
#pragma unroll
    for (int n = 0; n < 4; ++n) {
      int s = n * 16 + lr;
      off[kk][n] = s * 64 + (((kk * 4 + lg) ^ (s & 7)) * 8);
    }
  const int xw = (lr & 7) << 2;  // Ps word-swizzle

  const int rr = t >> 3, cbb = t & 7;
  const int swz = (cbb ^ (rr & 7)) * 8;
  const u16* Kg = qkb + (size_t)(b * 2048) * 2048 + 1024 + h * 64;
  const u16* Vg = vtb + (size_t)(b * 1024 + h * 64) * 2048;
  const u16* kp0 = Kg + (size_t)rr * 2048 + swz;
  const u16* vp0 = Vg + (size_t)rr * 2048 + swz;
  u32* Pw = &Ps[w][0];

#define ASTAGE(bb, tv)                                   \
  {                                                      \
    const u16* kp = kp0 + (size_t)(tv)*131072;           \
    const u16* vp = vp0 + (tv)*64;                       \
    GLDS16(kp, &Ks[bb][t * 8]);                          \
    GLDS16(kp + 65536, &Ks[bb][2048 + t * 8]);           \
    GLDS16(vp, &Vts[bb][t * 8]);                         \
    GLDS16(vp + 65536, &Vts[bb][2048 + t * 8]);          \
  }

  ASTAGE(0, 0);
  for (int tv = 0; tv < 32; ++tv) {
    const int bb = tv & 1;
    if (tv < 31) {
      ASTAGE(bb ^ 1, tv + 1);  // issue next tile first
      WAIT_VM4();              // only current tile's loads must have landed
    } else {
      WAIT_VM0();
    }
    RAWBAR();

    // S^T = K * Q^T : lane holds S[q=lr][k = 16n + 4lg + j]
    f32x4 sacc[4] = {};
    __builtin_amdgcn_s_setprio(1);
#pragma unroll
    for (int kk = 0; kk < 2; ++kk) {
      bf16x8 qf = kk ? qf1 : qf0;
#pragma unroll
      for (int n = 0; n < 4; ++n) {
        bf16x8 kf = *(const bf16x8*)&Ks[bb][off[kk][n]];
        sacc[n] = __builtin_amdgcn_mfma_f32_16x16x32_bf16(kf, qf, sacc[n], 0, 0, 0);
      }
    }
    __builtin_amdgcn_s_setprio(0);

    // in-register online softmax (exp2 domain, scale pre-folded into Q)
    float t0 = fmaxf(fmaxf(sacc[0][0], sacc[0][1]), sacc[0][2]);
    float t1 = fmaxf(fmaxf(sacc[0][3], sacc[1][0]), sacc[1][1]);
    float t2 = fmaxf(fmaxf(sacc[1][2], sacc[1][3]), sacc[2][0]);
    float t3 = fmaxf(fmaxf(sacc[2][1], sacc[2][2]), sacc[2][3]);
    float t4 = fmaxf(fmaxf(sacc[3][0], sacc[3][1]), sacc[3][2]);
    float pm = fmaxf(fmaxf(fmaxf(t0, t1), fmaxf(t2, t3)), fmaxf(t4, sacc[3][3]));
    pm = fmaxf(pm, __shfl_xor(pm, 16));
    pm = fmaxf(pm, __shfl_xor(pm, 32));

    if (__any(pm > mrun + 8.0f)) {  // T13 defer-max (rare after tile 0)
      float mnew = fmaxf(mrun, pm);
      float al = __builtin_amdgcn_exp2f(mrun - mnew);
      lrun *= al;
      float alj[4];
#pragma unroll
      for (int j = 0; j < 4; ++j) alj[j] = __shfl(al, 4 * lg + j);
#pragma unroll
      for (int n = 0; n < 4; ++n)
#pragma unroll
        for (int j = 0; j < 4; ++j) oacc[n][j] *= alj[j];
      mrun = mnew;
    }

    // fused exp + rowsum + pack
    float ps = 0.f;
#pragma unroll
    for (int n = 0; n < 4; ++n) {
      float v0 = __builtin_amdgcn_exp2f(sacc[n][0] - mrun);
      float v1 = __builtin_amdgcn_exp2f(sacc[n][1] - mrun);
      float v2 = __builtin_amdgcn_exp2f(sacc[n][2] - mrun);
      float v3 = __builtin_amdgcn_exp2f(sacc[n][3] - mrun);
      ps += (v0 + v1) + (v2 + v3);
      Pw[lr * 32 + ((8 * n + 2 * lg) ^ xw)] = cvt_pk(v0, v1);
      Pw[lr * 32 + ((8 * n + 2 * lg + 1) ^ xw)] = cvt_pk(v2, v3);
    }
    ps += __shfl_xor(ps, 16);
    ps += __shfl_xor(ps, 32);
    lrun += ps;

    // PV: A-frag = P[q=lr][k=32kk+8lg..+7] (same-wave DS, in-order)
    __builtin_amdgcn_s_setprio(1);
#pragma unroll
    for (int kk = 0; kk < 2; ++kk) {
      bf16x8 pa = *(const bf16x8*)&Pw[lr * 32 + ((16 * kk + 4 * lg) ^ xw)];
#pragma unroll
      for (int n = 0; n < 4; ++n) {
        bf16x8 vf = *(const bf16x8*)&Vts[bb][off[kk][n]];
        oacc[n] = __builtin_amdgcn_mfma_f32_16x16x32_bf16(pa, vf, oacc[n], 0, 0, 0);
      }
    }
    __builtin_amdgcn_s_setprio(0);
    RAWBAR();  // bounds skew; no drain needed (frags consumed)
  }
#undef ASTAGE

  float rinv = __builtin_amdgcn_rcpf(lrun);
  float rj[4];
#pragma unroll
  for (int j = 0; j < 4; ++j) rj[j] = __shfl(rinv, 4 * lg + j);
  int rowg = b * 2048 + q0 + w * 16 + lg * 4;
#pragma unroll
  for (int n = 0; n < 4; ++n) {
    int col = h * 64 + n * 16 + lr;
#pragma unroll
    for (int j = 0; j < 4; ++j)
      hb[(size_t)(rowg + j) * 1024 + col] = f2bf(oacc[n][j] * rj[j]);
  }
}

extern "C" void kernel_launch(void* const* d_in, const int* in_sizes, int n_in,
                              void* d_out, int out_size, void* d_ws,
                              size_t ws_size, hipStream_t stream) {
  const float* x = (const float*)d_in[0];
  const float* wq = (const float*)d_in[1];
  const float* wk = (const float*)d_in[2];
  const float* wv = (const float*)d_in[3];
  const float* wo = (const float*)d_in[4];

  u16* xb = (u16*)d_ws;              // [4096][1024]        4M
  u16* wqkv = xb + 4 * 1024 * 1024;  // [3072][1024]        3M
  u16* wot = wqkv + 3 * 1024 * 1024; // [1024][1024]        1M
  u16* qkb = wot + 1024 * 1024;      // [4096][2048] Q|K    8M
  u16* vtb = qkb + 8 * 1024 * 1024;  // [2][1024][2048] Vt  4M
  u16* hb = vtb + 4 * 1024 * 1024;   // [4096][1024] heads  4M

  cast_x<<<2048, 256, 0, stream>>>(x, xb);
  cast_wqkv<<<12288, 256, 0, stream>>>(wq, wk, wv, wqkv);
  cast_wo<<<4096, 256, 0, stream>>>(wo, wot);
  gemm_bt<2><<<dim3(24, 32), 256, 0, stream>>>(xb, wqkv, qkb, vtb, 4096, 3072, 1024);
  attn<<<1024, 256, 0, stream>>>(qkb, vtb, hb);
  gemm_bt<1><<<dim3(8, 32), 256, 0, stream>>>(hb, wot, d_out, nullptr, 4096, 1024, 1024);
}

// Round 7
// 151.121 us; speedup vs baseline: 1.0968x; 1.0104x over previous
//
#include <hip/hip_runtime.h>

typedef __attribute__((ext_vector_type(8))) short bf16x8;
typedef __attribute__((ext_vector_type(4))) float f32x4;
typedef __attribute__((ext_vector_type(4))) unsigned short u16x4;
typedef unsigned short u16;
typedef unsigned int u32;

static __device__ __forceinline__ u16 f2bf(float f) {
  u32 u = __float_as_uint(f);
  u32 r = (u + 0x7fffu + ((u >> 16) & 1u)) >> 16;  // RNE
  return (u16)r;
}

static __device__ __forceinline__ u32 cvt_pk(float lo, float hi) {
  u32 r;
  asm("v_cvt_pk_bf16_f32 %0, %1, %2" : "=v"(r) : "v"(lo), "v"(hi));
  return r;
}

#define GLDS16(g, l)                                                        \
  __builtin_amdgcn_global_load_lds(                                         \
      (const __attribute__((address_space(1))) u32*)(g),                    \
      (__attribute__((address_space(3))) u32*)(l), 16, 0, 0)

#define WAIT_VM3() asm volatile("s_waitcnt vmcnt(3)" ::: "memory")
#define WAIT_VM4() asm volatile("s_waitcnt vmcnt(4)" ::: "memory")
#define WAIT_VM0() asm volatile("s_waitcnt vmcnt(0)" ::: "memory")
#define RAWBAR() __builtin_amdgcn_s_barrier()

#define SC2F 0.18033688011112042f  // 0.125 * log2(e)

// ---------------- cast kernels ----------------
__global__ __launch_bounds__(256) void cast_x(const float* __restrict__ x,
                                              u16* __restrict__ xb) {
  int i = blockIdx.x * 256 + threadIdx.x;  // one thread per 8 elems
  const float4* xv = (const float4*)x;
  float4 a = xv[i * 2], b = xv[i * 2 + 1];
  bf16x8 o;
  o[0] = f2bf(a.x); o[1] = f2bf(a.y); o[2] = f2bf(a.z); o[3] = f2bf(a.w);
  o[4] = f2bf(b.x); o[5] = f2bf(b.y); o[6] = f2bf(b.z); o[7] = f2bf(b.w);
  *(bf16x8*)(xb + i * 8) = o;
}

// Wqkv_t[n][d], n = sel*1024 + h*64 + kk; value = W_sel[h][d][kk]
__global__ __launch_bounds__(256) void cast_wqkv(const float* __restrict__ wq,
                                                 const float* __restrict__ wk,
                                                 const float* __restrict__ wv,
                                                 u16* __restrict__ wt) {
  int tid = blockIdx.x * 256 + threadIdx.x;  // 3M
  int n = tid >> 10, d = tid & 1023;
  int sel = n >> 10, r = n & 1023, h = r >> 6, kk = r & 63;
  const float* src = sel == 0 ? wq : (sel == 1 ? wk : wv);
  wt[tid] = f2bf(src[h * 65536 + d * 64 + kk]);
}

// WOt[n][k] = W_O[k][n]
__global__ __launch_bounds__(256) void cast_wo(const float* __restrict__ wo,
                                               u16* __restrict__ wt) {
  int tid = blockIdx.x * 256 + threadIdx.x;  // 1M
  int n = tid >> 10, k = tid & 1023;
  wt[tid] = f2bf(wo[k * 1024 + n]);
}

// ---------------- QKV GEMM: 256x128 tile, 512 threads, BK=32 -------------
// L2-staging-BW-bound at 128^2 => bigger tile: 192B staged/MFMA vs 256B.
// qkb[row][col] (Q cols scaled) for col<2048; Vt transposed for col>=2048.
__global__ __launch_bounds__(512) void gemm_qkv(const u16* __restrict__ A,
                                                const u16* __restrict__ Bt,
                                                u16* __restrict__ qkb,
                                                u16* __restrict__ Vt, int M,
                                                int N, int K) {
  const int t = threadIdx.x;
  const int lane = t & 63, w = t >> 6;
  const int lr = lane & 15, lg = lane >> 4;
  const int wr = w >> 1, wc = w & 1;  // 4M x 2N waves, 64x64 each
  int lin = blockIdx.y * gridDim.x + blockIdx.x;
  int nwg = gridDim.x * gridDim.y;
  int swz = (lin & 7) * (nwg >> 3) + (lin >> 3);
  int bx = swz % gridDim.x, by = swz / gridDim.x;
  const int m0 = by * 256, n0 = bx * 128;
  __shared__ __align__(16) u16 As[2][256 * 32];
  __shared__ __align__(16) u16 Bs[2][128 * 32];
  const int ra = t >> 2, ca = (t & 3) * 8;  // ra in [0,128)
  const u16* a0 = A + (size_t)(m0 + ra) * K + ca;
  const u16* b0 = Bt + (size_t)(n0 + ra) * K + ca;
  const size_t ajmp = (size_t)128 * K;
  f32x4 acc[4][4] = {};

#define QSTAGE(bb, k0)                                 \
  {                                                    \
    GLDS16(a0 + (k0), &As[bb][t * 8]);                 \
    GLDS16(a0 + ajmp + (k0), &As[bb][4096 + t * 8]);   \
    GLDS16(b0 + (k0), &Bs[bb][t * 8]);                 \
  }

  QSTAGE(0, 0);
  for (int k0 = 0; k0 < K; k0 += 32) {
    const int bb = (k0 >> 5) & 1;
    if (k0 + 32 < K) {
      QSTAGE(bb ^ 1, k0 + 32);  // issue next tile first
      WAIT_VM3();               // current tile's 3 loads landed
    } else {
      WAIT_VM0();
    }
    RAWBAR();
    bf16x8 a[4], b[4];
#pragma unroll
    for (int m = 0; m < 4; ++m)
      a[m] = *(const bf16x8*)&As[bb][(wr * 64 + m * 16 + lr) * 32 + lg * 8];
#pragma unroll
    for (int n = 0; n < 4; ++n)
      b[n] = *(const bf16x8*)&Bs[bb][(wc * 64 + n * 16 + lr) * 32 + lg * 8];
    __builtin_amdgcn_s_setprio(1);
#pragma unroll
    for (int m = 0; m < 4; ++m)
#pragma unroll
      for (int n = 0; n < 4; ++n)
        acc[m][n] =
            __builtin_amdgcn_mfma_f32_16x16x32_bf16(a[m], b[n], acc[m][n], 0, 0, 0);
    __builtin_amdgcn_s_setprio(0);
    RAWBAR();
  }
#undef QSTAGE

#pragma unroll
  for (int m = 0; m < 4; ++m) {
    int rowg = m0 + wr * 64 + m * 16 + lg * 4;
#pragma unroll
    for (int n = 0; n < 4; ++n) {
      int colg = n0 + wc * 64 + n * 16 + lr;
      if (colg < 1024) {  // Q: fold softmax scale (exp2 domain)
#pragma unroll
        for (int j = 0; j < 4; ++j)
          qkb[(size_t)(rowg + j) * 2048 + colg] = f2bf(acc[m][n][j] * SC2F);
      } else if (colg < 2048) {  // K
#pragma unroll
        for (int j = 0; j < 4; ++j)
          qkb[(size_t)(rowg + j) * 2048 + colg] = f2bf(acc[m][n][j]);
      } else {  // V, stored transposed [dk_total][S]
        int vidx = colg - 2048, bb2 = rowg >> 11, s = rowg & 2047;
        u16x4 pk;
#pragma unroll
        for (int j = 0; j < 4; ++j) pk[j] = f2bf(acc[m][n][j]);
        *(u16x4*)(Vt + (size_t)(bb2 * 1024 + vidx) * 2048 + s) = pk;
      }
    }
  }
}

// ---------------- out-proj GEMM: 128x128 tile (f32 C) ---------------------
__global__ __launch_bounds__(256) void gemm_out(const u16* __restrict__ A,
                                                const u16* __restrict__ Bt,
                                                float* __restrict__ C, int M,
                                                int N, int K) {
  const int t = threadIdx.x;
  const int lane = t & 63, w = t >> 6;
  const int lr = lane & 15, lg = lane >> 4;
  const int wr = w >> 1, wc = w & 1;
  int lin = blockIdx.y * gridDim.x + blockIdx.x;
  int nwg = gridDim.x * gridDim.y;
  int swz = (lin & 7) * (nwg >> 3) + (lin >> 3);
  int bx = swz % gridDim.x, by = swz / gridDim.x;
  const int m0 = by * 128, n0 = bx * 128;
  __shared__ __align__(16) u16 As[2][128 * 32];
  __shared__ __align__(16) u16 Bs[2][128 * 32];
  const int r0 = t >> 2, cb = (t & 3) * 8;
  const u16* a0 = A + (size_t)(m0 + r0) * K + cb;
  const u16* b0 = Bt + (size_t)(n0 + r0) * K + cb;
  const size_t rowjmp = (size_t)64 * K;
  f32x4 acc[4][4] = {};

#define GSTAGE(bb, k0)                                      \
  {                                                         \
    GLDS16(a0 + (k0), &As[bb][t * 8]);                      \
    GLDS16(a0 + rowjmp + (k0), &As[bb][2048 + t * 8]);      \
    GLDS16(b0 + (k0), &Bs[bb][t * 8]);                      \
    GLDS16(b0 + rowjmp + (k0), &Bs[bb][2048 + t * 8]);      \
  }

  GSTAGE(0, 0);
  for (int k0 = 0; k0 < K; k0 += 32) {
    const int bb = (k0 >> 5) & 1;
    if (k0 + 32 < K) {
      GSTAGE(bb ^ 1, k0 + 32);
      WAIT_VM4();
    } else {
      WAIT_VM0();
    }
    RAWBAR();
    bf16x8 a[4], b[4];
#pragma unroll
    for (int m = 0; m < 4; ++m)
      a[m] = *(const bf16x8*)&As[bb][(wr * 64 + m * 16 + lr) * 32 + lg * 8];
#pragma unroll
    for (int n = 0; n < 4; ++n)
      b[n] = *(const bf16x8*)&Bs[bb][(wc * 64 + n * 16 + lr) * 32 + lg * 8];
    __builtin_amdgcn_s_setprio(1);
#pragma unroll
    for (int m = 0; m < 4; ++m)
#pragma unroll
      for (int n = 0; n < 4; ++n)
        acc[m][n] =
            __builtin_amdgcn_mfma_f32_16x16x32_bf16(a[m], b[n], acc[m][n], 0, 0, 0);
    __builtin_amdgcn_s_setprio(0);
    RAWBAR();
  }
#undef GSTAGE

#pragma unroll
  for (int m = 0; m < 4; ++m) {
    int rowg = m0 + wr * 64 + m * 16 + lg * 4;
#pragma unroll
    for (int n = 0; n < 4; ++n) {
      int colg = n0 + wc * 64 + n * 16 + lr;
#pragma unroll
      for (int j = 0; j < 4; ++j)
        C[(size_t)(rowg + j) * N + colg] = acc[m][n][j];
    }
  }
}

// ---------------- flash attention (swapped QK^T, counted-vmcnt dbuf) ------
// grid: 1024 blocks = (b,h) * 32 q-tiles of 64 rows; 4 waves * 16 q-rows.
// XCD swizzle: 128 consecutive tiles (4 (b,h) groups = 2MB K/V) per XCD.
// l-reduction deferred to epilogue (per-lane partials; alpha row-uniform).
// LDS = 16K Kdbuf + 16K Vdbuf + 8K Ps = 40960 B => 4 blocks/CU.
__global__ __launch_bounds__(256) void attn(const u16* __restrict__ qkb,
                                            const u16* __restrict__ vtb,
                                            u16* __restrict__ hb) {
  const int t = threadIdx.x, lane = t & 63, w = t >> 6;
  const int lr = lane & 15, lg = lane >> 4;
  int lin = blockIdx.x;
  int swz2 = (lin & 7) * 128 + (lin >> 3);  // T1: same-(b,h) blocks share XCD
  int qi = swz2 & 31, bh = swz2 >> 5;
  int b = bh >> 4, h = bh & 15;
  int q0 = qi * 64;
  __shared__ __align__(16) u16 Ks[2][64 * 64];   // [s][dk], chunk^=(s&7)
  __shared__ __align__(16) u16 Vts[2][64 * 64];  // [dk][s], chunk^=(d&7)
  __shared__ __align__(16) u32 Ps[4][16 * 32];   // per-wave packed P, swizzled

  const u16* qbase = qkb + (size_t)(b * 2048 + q0 + w * 16 + lr) * 2048 + h * 64;
  bf16x8 qf0 = *(const bf16x8*)(qbase + lg * 8);
  bf16x8 qf1 = *(const bf16x8*)(qbase + 32 + lg * 8);

  f32x4 oacc[4] = {};
  float mrun = -1e30f, lrun = 0.f;  // lrun = per-lane PARTIAL sum

  int off[2][4];
#pragma unroll
  for (int kk = 0; kk < 2; ++kk)
#pragma unroll
    for (int n = 0; n < 4; ++n) {
      int s = n * 16 + lr;
      off[kk][n] = s * 64 + (((kk * 4 + lg) ^ (s & 7)) * 8);
    }
  const int xw = (lr & 7) << 2;  // Ps word-swizzle

  const int rr = t >> 3, cbb = t & 7;
  const int swz = (cbb ^ (rr & 7)) * 8;
  const u16* Kg = qkb + (size_t)(b * 2048) * 2048 + 1024 + h * 64;
  const u16* Vg = vtb + (size_t)(b * 1024 + h * 64) * 2048;
  const u16* kp0 = Kg + (size_t)rr * 2048 + swz;
  const u16* vp0 = Vg + (size_t)rr * 2048 + swz;
  u32* Pw = &Ps[w][0];

#define ASTAGE(bb, tv)                                   \
  {                                                      \
    const u16* kp = kp0 + (size_t)(tv)*131072;           \
    const u16* vp = vp0 + (tv)*64;                       \
    GLDS16(kp, &Ks[bb][t * 8]);                          \
    GLDS16(kp + 65536, &Ks[bb][2048 + t * 8]);           \
    GLDS16(vp, &Vts[bb][t * 8]);                         \
    GLDS16(vp + 65536, &Vts[bb][2048 + t * 8]);          \
  }

  ASTAGE(0, 0);
  for (int tv = 0; tv < 32; ++tv) {
    const int bb = tv & 1;
    if (tv < 31) {
      ASTAGE(bb ^ 1, tv + 1);  // issue next tile first
      WAIT_VM4();              // only current tile's loads must have landed
    } else {
      WAIT_VM0();
    }
    RAWBAR();

    // S^T = K * Q^T : lane holds S[q=lr][k = 16n + 4lg + j]
    f32x4 sacc[4] = {};
    __builtin_amdgcn_s_setprio(1);
#pragma unroll
    for (int kk = 0; kk < 2; ++kk) {
      bf16x8 qf = kk ? qf1 : qf0;
#pragma unroll
      for (int n = 0; n < 4; ++n) {
        bf16x8 kf = *(const bf16x8*)&Ks[bb][off[kk][n]];
        sacc[n] = __builtin_amdgcn_mfma_f32_16x16x32_bf16(kf, qf, sacc[n], 0, 0, 0);
      }
    }
    __builtin_amdgcn_s_setprio(0);

    // in-register online softmax (exp2 domain, scale pre-folded into Q)
    float t0 = fmaxf(fmaxf(sacc[0][0], sacc[0][1]), sacc[0][2]);
    float t1 = fmaxf(fmaxf(sacc[0][3], sacc[1][0]), sacc[1][1]);
    float t2 = fmaxf(fmaxf(sacc[1][2], sacc[1][3]), sacc[2][0]);
    float t3 = fmaxf(fmaxf(sacc[2][1], sacc[2][2]), sacc[2][3]);
    float t4 = fmaxf(fmaxf(sacc[3][0], sacc[3][1]), sacc[3][2]);
    float pm = fmaxf(fmaxf(fmaxf(t0, t1), fmaxf(t2, t3)), fmaxf(t4, sacc[3][3]));
    pm = fmaxf(pm, __shfl_xor(pm, 16));
    pm = fmaxf(pm, __shfl_xor(pm, 32));

    if (__any(pm > mrun + 8.0f)) {  // T13 defer-max (rare after tile 0)
      float mnew = fmaxf(mrun, pm);
      float al = __builtin_amdgcn_exp2f(mrun - mnew);  // row-uniform
      lrun *= al;                                      // scales partials ok
      float alj[4];
#pragma unroll
      for (int j = 0; j < 4; ++j) alj[j] = __shfl(al, 4 * lg + j);
#pragma unroll
      for (int n = 0; n < 4; ++n)
#pragma unroll
        for (int j = 0; j < 4; ++j) oacc[n][j] *= alj[j];
      mrun = mnew;
    }

    // fused exp + per-lane partial rowsum + pack (cross-lane sum deferred)
    float ps = 0.f;
#pragma unroll
    for (int n = 0; n < 4; ++n) {
      float v0 = __builtin_amdgcn_exp2f(sacc[n][0] - mrun);
      float v1 = __builtin_amdgcn_exp2f(sacc[n][1] - mrun);
      float v2 = __builtin_amdgcn_exp2f(sacc[n][2] - mrun);
      float v3 = __builtin_amdgcn_exp2f(sacc[n][3] - mrun);
      ps += (v0 + v1) + (v2 + v3);
      Pw[lr * 32 + ((8 * n + 2 * lg) ^ xw)] = cvt_pk(v0, v1);
      Pw[lr * 32 + ((8 * n + 2 * lg + 1) ^ xw)] = cvt_pk(v2, v3);
    }
    lrun += ps;

    // PV: A-frag = P[q=lr][k=32kk+8lg..+7] (same-wave DS, in-order)
    __builtin_amdgcn_s_setprio(1);
#pragma unroll
    for (int kk = 0; kk < 2; ++kk) {
      bf16x8 pa = *(const bf16x8*)&Pw[lr * 32 + ((16 * kk + 4 * lg) ^ xw)];
#pragma unroll
      for (int n = 0; n < 4; ++n) {
        bf16x8 vf = *(const bf16x8*)&Vts[bb][off[kk][n]];
        oacc[n] = __builtin_amdgcn_mfma_f32_16x16x32_bf16(pa, vf, oacc[n], 0, 0, 0);
      }
    }
    __builtin_amdgcn_s_setprio(0);
    RAWBAR();  // bounds skew; no drain needed (frags consumed)
  }
#undef ASTAGE

  // epilogue: finish l reduction (4 lanes per q-row), then normalize
  lrun += __shfl_xor(lrun, 16);
  lrun += __shfl_xor(lrun, 32);
  float rinv = __builtin_amdgcn_rcpf(lrun);
  float rj[4];
#pragma unroll
  for (int j = 0; j < 4; ++j) rj[j] = __shfl(rinv, 4 * lg + j);
  int rowg = b * 2048 + q0 + w * 16 + lg * 4;
#pragma unroll
  for (int n = 0; n < 4; ++n) {
    int col = h * 64 + n * 16 + lr;
#pragma unroll
    for (int j = 0; j < 4; ++j)
      hb[(size_t)(rowg + j) * 1024 + col] = f2bf(oacc[n][j] * rj[j]);
  }
}

extern "C" void kernel_launch(void* const* d_in, const int* in_sizes, int n_in,
                              void* d_out, int out_size, void* d_ws,
                              size_t ws_size, hipStream_t stream) {
  const float* x = (const float*)d_in[0];
  const float* wq = (const float*)d_in[1];
  const float* wk = (const float*)d_in[2];
  const float* wv = (const float*)d_in[3];
  const float* wo = (const float*)d_in[4];

  u16* xb = (u16*)d_ws;              // [4096][1024]        4M
  u16* wqkv = xb + 4 * 1024 * 1024;  // [3072][1024]        3M
  u16* wot = wqkv + 3 * 1024 * 1024; // [1024][1024]        1M
  u16* qkb = wot + 1024 * 1024;      // [4096][2048] Q|K    8M
  u16* vtb = qkb + 8 * 1024 * 1024;  // [2][1024][2048] Vt  4M
  u16* hb = vtb + 4 * 1024 * 1024;   // [4096][1024] heads  4M

  cast_x<<<2048, 256, 0, stream>>>(x, xb);
  cast_wqkv<<<12288, 256, 0, stream>>>(wq, wk, wv, wqkv);
  cast_wo<<<4096, 256, 0, stream>>>(wo, wot);
  gemm_qkv<<<dim3(24, 16), 512, 0, stream>>>(xb, wqkv, qkb, vtb, 4096, 3072, 1024);
  attn<<<1024, 256, 0, stream>>>(qkb, vtb, hb);
  gemm_out<<<dim3(8, 32), 256, 0, stream>>>(hb, wot, (float*)d_out, 4096, 1024, 1024);
}

// Round 8
// 141.809 us; speedup vs baseline: 1.1689x; 1.0657x over previous
//
#include <hip/hip_runtime.h>

typedef __attribute__((ext_vector_type(8))) short bf16x8;
typedef __attribute__((ext_vector_type(4))) float f32x4;
typedef __attribute__((ext_vector_type(4))) unsigned short u16x4;
typedef unsigned short u16;
typedef unsigned int u32;

static __device__ __forceinline__ u16 f2bf(float f) {
  u32 u = __float_as_uint(f);
  u32 r = (u + 0x7fffu + ((u >> 16) & 1u)) >> 16;  // RNE
  return (u16)r;
}

static __device__ __forceinline__ u32 cvt_pk(float lo, float hi) {
  u32 r;
  asm("v_cvt_pk_bf16_f32 %0, %1, %2" : "=v"(r) : "v"(lo), "v"(hi));
  return r;
}

#define GLDS16(g, l)                                                        \
  __builtin_amdgcn_global_load_lds(                                         \
      (const __attribute__((address_space(1))) u32*)(g),                    \
      (__attribute__((address_space(3))) u32*)(l), 16, 0, 0)

#define WAIT_VM3() asm volatile("s_waitcnt vmcnt(3)" ::: "memory")
#define WAIT_VM4() asm volatile("s_waitcnt vmcnt(4)" ::: "memory")
#define WAIT_VM0() asm volatile("s_waitcnt vmcnt(0)" ::: "memory")
#define RAWBAR() __builtin_amdgcn_s_barrier()

#define SC2F 0.18033688011112042f  // 0.125 * log2(e)

// ---------------- cast kernels ----------------
__global__ __launch_bounds__(256) void cast_x(const float* __restrict__ x,
                                              u16* __restrict__ xb) {
  int i = blockIdx.x * 256 + threadIdx.x;  // one thread per 8 elems
  const float4* xv = (const float4*)x;
  float4 a = xv[i * 2], b = xv[i * 2 + 1];
  bf16x8 o;
  o[0] = f2bf(a.x); o[1] = f2bf(a.y); o[2] = f2bf(a.z); o[3] = f2bf(a.w);
  o[4] = f2bf(b.x); o[5] = f2bf(b.y); o[6] = f2bf(b.z); o[7] = f2bf(b.w);
  *(bf16x8*)(xb + i * 8) = o;
}

// Wqkv_t[n][d], n = sel*1024 + h*64 + kk; value = W_sel[h][d][kk]
__global__ __launch_bounds__(256) void cast_wqkv(const float* __restrict__ wq,
                                                 const float* __restrict__ wk,
                                                 const float* __restrict__ wv,
                                                 u16* __restrict__ wt) {
  int tid = blockIdx.x * 256 + threadIdx.x;  // 3M
  int n = tid >> 10, d = tid & 1023;
  int sel = n >> 10, r = n & 1023, h = r >> 6, kk = r & 63;
  const float* src = sel == 0 ? wq : (sel == 1 ? wk : wv);
  wt[tid] = f2bf(src[h * 65536 + d * 64 + kk]);
}

// WOt[n][k] = W_O[k][n]
__global__ __launch_bounds__(256) void cast_wo(const float* __restrict__ wo,
                                               u16* __restrict__ wt) {
  int tid = blockIdx.x * 256 + threadIdx.x;  // 1M
  int n = tid >> 10, k = tid & 1023;
  wt[tid] = f2bf(wo[k * 1024 + n]);
}

// ---------------- QKV GEMM: 256x128 tile, 512 threads, BK=32 -------------
__global__ __launch_bounds__(512) void gemm_qkv(const u16* __restrict__ A,
                                                const u16* __restrict__ Bt,
                                                u16* __restrict__ qkb,
                                                u16* __restrict__ Vt, int M,
                                                int N, int K) {
  const int t = threadIdx.x;
  const int lane = t & 63, w = t >> 6;
  const int lr = lane & 15, lg = lane >> 4;
  const int wr = w >> 1, wc = w & 1;  // 4M x 2N waves, 64x64 each
  int lin = blockIdx.y * gridDim.x + blockIdx.x;
  int nwg = gridDim.x * gridDim.y;
  int swz = (lin & 7) * (nwg >> 3) + (lin >> 3);
  int bx = swz % gridDim.x, by = swz / gridDim.x;
  const int m0 = by * 256, n0 = bx * 128;
  __shared__ __align__(16) u16 As[2][256 * 32];
  __shared__ __align__(16) u16 Bs[2][128 * 32];
  const int ra = t >> 2, ca = (t & 3) * 8;  // ra in [0,128)
  const u16* a0 = A + (size_t)(m0 + ra) * K + ca;
  const u16* b0 = Bt + (size_t)(n0 + ra) * K + ca;
  const size_t ajmp = (size_t)128 * K;
  f32x4 acc[4][4] = {};

#define QSTAGE(bb, k0)                                 \
  {                                                    \
    GLDS16(a0 + (k0), &As[bb][t * 8]);                 \
    GLDS16(a0 + ajmp + (k0), &As[bb][4096 + t * 8]);   \
    GLDS16(b0 + (k0), &Bs[bb][t * 8]);                 \
  }

  QSTAGE(0, 0);
  for (int k0 = 0; k0 < K; k0 += 32) {
    const int bb = (k0 >> 5) & 1;
    if (k0 + 32 < K) {
      QSTAGE(bb ^ 1, k0 + 32);  // issue next tile first
      WAIT_VM3();               // current tile's 3 loads landed
    } else {
      WAIT_VM0();
    }
    RAWBAR();
    bf16x8 a[4], b[4];
#pragma unroll
    for (int m = 0; m < 4; ++m)
      a[m] = *(const bf16x8*)&As[bb][(wr * 64 + m * 16 + lr) * 32 + lg * 8];
#pragma unroll
    for (int n = 0; n < 4; ++n)
      b[n] = *(const bf16x8*)&Bs[bb][(wc * 64 + n * 16 + lr) * 32 + lg * 8];
    __builtin_amdgcn_s_setprio(1);
#pragma unroll
    for (int m = 0; m < 4; ++m)
#pragma unroll
      for (int n = 0; n < 4; ++n)
        acc[m][n] =
            __builtin_amdgcn_mfma_f32_16x16x32_bf16(a[m], b[n], acc[m][n], 0, 0, 0);
    __builtin_amdgcn_s_setprio(0);
    RAWBAR();
  }
#undef QSTAGE

#pragma unroll
  for (int m = 0; m < 4; ++m) {
    int rowg = m0 + wr * 64 + m * 16 + lg * 4;
#pragma unroll
    for (int n = 0; n < 4; ++n) {
      int colg = n0 + wc * 64 + n * 16 + lr;
      if (colg < 1024) {  // Q: fold softmax scale (exp2 domain)
#pragma unroll
        for (int j = 0; j < 4; ++j)
          qkb[(size_t)(rowg + j) * 2048 + colg] = f2bf(acc[m][n][j] * SC2F);
      } else if (colg < 2048) {  // K
#pragma unroll
        for (int j = 0; j < 4; ++j)
          qkb[(size_t)(rowg + j) * 2048 + colg] = f2bf(acc[m][n][j]);
      } else {  // V, stored transposed [dk_total][S]
        int vidx = colg - 2048, bb2 = rowg >> 11, s = rowg & 2047;
        u16x4 pk;
#pragma unroll
        for (int j = 0; j < 4; ++j) pk[j] = f2bf(acc[m][n][j]);
        *(u16x4*)(Vt + (size_t)(bb2 * 1024 + vidx) * 2048 + s) = pk;
      }
    }
  }
}

// ---------------- out-proj GEMM: 128x128 tile (f32 C) ---------------------
__global__ __launch_bounds__(256) void gemm_out(const u16* __restrict__ A,
                                                const u16* __restrict__ Bt,
                                                float* __restrict__ C, int M,
                                                int N, int K) {
  const int t = threadIdx.x;
  const int lane = t & 63, w = t >> 6;
  const int lr = lane & 15, lg = lane >> 4;
  const int wr = w >> 1, wc = w & 1;
  int lin = blockIdx.y * gridDim.x + blockIdx.x;
  int nwg = gridDim.x * gridDim.y;
  int swz = (lin & 7) * (nwg >> 3) + (lin >> 3);
  int bx = swz % gridDim.x, by = swz / gridDim.x;
  const int m0 = by * 128, n0 = bx * 128;
  __shared__ __align__(16) u16 As[2][128 * 32];
  __shared__ __align__(16) u16 Bs[2][128 * 32];
  const int r0 = t >> 2, cb = (t & 3) * 8;
  const u16* a0 = A + (size_t)(m0 + r0) * K + cb;
  const u16* b0 = Bt + (size_t)(n0 + r0) * K + cb;
  const size_t rowjmp = (size_t)64 * K;
  f32x4 acc[4][4] = {};

#define GSTAGE(bb, k0)                                      \
  {                                                         \
    GLDS16(a0 + (k0), &As[bb][t * 8]);                      \
    GLDS16(a0 + rowjmp + (k0), &As[bb][2048 + t * 8]);      \
    GLDS16(b0 + (k0), &Bs[bb][t * 8]);                      \
    GLDS16(b0 + rowjmp + (k0), &Bs[bb][2048 + t * 8]);      \
  }

  GSTAGE(0, 0);
  for (int k0 = 0; k0 < K; k0 += 32) {
    const int bb = (k0 >> 5) & 1;
    if (k0 + 32 < K) {
      GSTAGE(bb ^ 1, k0 + 32);
      WAIT_VM4();
    } else {
      WAIT_VM0();
    }
    RAWBAR();
    bf16x8 a[4], b[4];
#pragma unroll
    for (int m = 0; m < 4; ++m)
      a[m] = *(const bf16x8*)&As[bb][(wr * 64 + m * 16 + lr) * 32 + lg * 8];
#pragma unroll
    for (int n = 0; n < 4; ++n)
      b[n] = *(const bf16x8*)&Bs[bb][(wc * 64 + n * 16 + lr) * 32 + lg * 8];
    __builtin_amdgcn_s_setprio(1);
#pragma unroll
    for (int m = 0; m < 4; ++m)
#pragma unroll
      for (int n = 0; n < 4; ++n)
        acc[m][n] =
            __builtin_amdgcn_mfma_f32_16x16x32_bf16(a[m], b[n], acc[m][n], 0, 0, 0);
    __builtin_amdgcn_s_setprio(0);
    RAWBAR();
  }
#undef GSTAGE

#pragma unroll
  for (int m = 0; m < 4; ++m) {
    int rowg = m0 + wr * 64 + m * 16 + lg * 4;
#pragma unroll
    for (int n = 0; n < 4; ++n) {
      int colg = n0 + wc * 64 + n * 16 + lr;
#pragma unroll
      for (int j = 0; j < 4; ++j)
        C[(size_t)(rowg + j) * N + colg] = acc[m][n][j];
    }
  }
}

// ---------------- flash attention: QBLK=128, 2 q-groups per wave ----------
// grid: 512 blocks = (b,h) * 16 q-tiles of 128 rows; 4 waves * 32 q-rows.
// Each kf/vf LDS fragment read feeds TWO q-group MFMAs (halves LDS read
// traffic per q-row — attn is LDS-BW-bound). R7-proven 2-barrier counted-
// vmcnt dbuf loop. LDS = 16K Kdbuf + 16K Vdbuf + 16K Ps = 48 KB; grid caps
// at 2 blocks/CU so LDS is not the limiter.
__global__ __launch_bounds__(256, 2) void attn(const u16* __restrict__ qkb,
                                               const u16* __restrict__ vtb,
                                               u16* __restrict__ hb) {
  const int t = threadIdx.x, lane = t & 63, w = t >> 6;
  const int lr = lane & 15, lg = lane >> 4;
  int lin = blockIdx.x;
  int swz2 = (lin & 7) * 64 + (lin >> 3);  // T1: same-(b,h) blocks share XCD
  int qi = swz2 & 15, bh = swz2 >> 4;
  int b = bh >> 4, h = bh & 15;
  int q0 = qi * 128;
  __shared__ __align__(16) u16 Ks[2][64 * 64];   // [s][dk], chunk^=(s&7)
  __shared__ __align__(16) u16 Vts[2][64 * 64];  // [dk][s], chunk^=(d&7)
  __shared__ __align__(16) u32 Ps[4][2][512];    // per-wave, per-group P

  bf16x8 qf[2][2];
#pragma unroll
  for (int g = 0; g < 2; ++g) {
    const u16* qb =
        qkb + (size_t)(b * 2048 + q0 + w * 32 + g * 16 + lr) * 2048 + h * 64;
    qf[g][0] = *(const bf16x8*)(qb + lg * 8);
    qf[g][1] = *(const bf16x8*)(qb + 32 + lg * 8);
  }

  f32x4 oacc[2][4] = {};
  float mrun0 = -1e30f, mrun1 = -1e30f;
  float lrun0 = 0.f, lrun1 = 0.f;  // per-lane partial sums

  int off[2][4];
#pragma unroll
  for (int kk = 0; kk < 2; ++kk)
#pragma unroll
    for (int n = 0; n < 4; ++n) {
      int s = n * 16 + lr;
      off[kk][n] = s * 64 + (((kk * 4 + lg) ^ (s & 7)) * 8);
    }
  const int xw = (lr & 7) << 2;  // Ps word-swizzle

  const int rr = t >> 3, cbb = t & 7;
  const int swz = (cbb ^ (rr & 7)) * 8;
  const u16* Kg = qkb + (size_t)(b * 2048) * 2048 + 1024 + h * 64;
  const u16* Vg = vtb + (size_t)(b * 1024 + h * 64) * 2048;
  const u16* kp0 = Kg + (size_t)rr * 2048 + swz;
  const u16* vp0 = Vg + (size_t)rr * 2048 + swz;
  u32* Pw0 = &Ps[w][0][0];
  u32* Pw1 = &Ps[w][1][0];

#define ASTAGE(bb, tv)                                   \
  {                                                      \
    const u16* kp = kp0 + (size_t)(tv)*131072;           \
    const u16* vp = vp0 + (tv)*64;                       \
    GLDS16(kp, &Ks[bb][t * 8]);                          \
    GLDS16(kp + 65536, &Ks[bb][2048 + t * 8]);           \
    GLDS16(vp, &Vts[bb][t * 8]);                         \
    GLDS16(vp + 65536, &Vts[bb][2048 + t * 8]);          \
  }

  ASTAGE(0, 0);
  for (int tv = 0; tv < 32; ++tv) {
    const int bb = tv & 1;
    if (tv < 31) {
      ASTAGE(bb ^ 1, tv + 1);  // issue next tile first
      WAIT_VM4();              // only current tile's loads must have landed
    } else {
      WAIT_VM0();
    }
    RAWBAR();

    // S^T = K * Q^T for both q-groups; each kf read feeds 2 MFMAs
    f32x4 s0[4] = {}, s1[4] = {};
    __builtin_amdgcn_s_setprio(1);
#pragma unroll
    for (int kk = 0; kk < 2; ++kk)
#pragma unroll
      for (int n = 0; n < 4; ++n) {
        bf16x8 kf = *(const bf16x8*)&Ks[bb][off[kk][n]];
        s0[n] = __builtin_amdgcn_mfma_f32_16x16x32_bf16(kf, qf[0][kk], s0[n], 0, 0, 0);
        s1[n] = __builtin_amdgcn_mfma_f32_16x16x32_bf16(kf, qf[1][kk], s1[n], 0, 0, 0);
      }
    __builtin_amdgcn_s_setprio(0);

    // softmax, group 0
    float a0 = fmaxf(fmaxf(s0[0][0], s0[0][1]), s0[0][2]);
    float a1 = fmaxf(fmaxf(s0[0][3], s0[1][0]), s0[1][1]);
    float a2 = fmaxf(fmaxf(s0[1][2], s0[1][3]), s0[2][0]);
    float a3 = fmaxf(fmaxf(s0[2][1], s0[2][2]), s0[2][3]);
    float a4 = fmaxf(fmaxf(s0[3][0], s0[3][1]), s0[3][2]);
    float pm0 = fmaxf(fmaxf(fmaxf(a0, a1), fmaxf(a2, a3)), fmaxf(a4, s0[3][3]));
    pm0 = fmaxf(pm0, __shfl_xor(pm0, 16));
    pm0 = fmaxf(pm0, __shfl_xor(pm0, 32));
    // softmax, group 1
    float c0 = fmaxf(fmaxf(s1[0][0], s1[0][1]), s1[0][2]);
    float c1 = fmaxf(fmaxf(s1[0][3], s1[1][0]), s1[1][1]);
    float c2 = fmaxf(fmaxf(s1[1][2], s1[1][3]), s1[2][0]);
    float c3 = fmaxf(fmaxf(s1[2][1], s1[2][2]), s1[2][3]);
    float c4 = fmaxf(fmaxf(s1[3][0], s1[3][1]), s1[3][2]);
    float pm1 = fmaxf(fmaxf(fmaxf(c0, c1), fmaxf(c2, c3)), fmaxf(c4, s1[3][3]));
    pm1 = fmaxf(pm1, __shfl_xor(pm1, 16));
    pm1 = fmaxf(pm1, __shfl_xor(pm1, 32));

    if (__any(fmaxf(pm0 - mrun0, pm1 - mrun1) > 8.0f)) {  // T13 defer-max
      {
        float mn = fmaxf(mrun0, pm0);
        float al = __builtin_amdgcn_exp2f(mrun0 - mn);
        lrun0 *= al;
        float alj[4];
#pragma unroll
        for (int j = 0; j < 4; ++j) alj[j] = __shfl(al, 4 * lg + j);
#pragma unroll
        for (int n = 0; n < 4; ++n)
#pragma unroll
          for (int j = 0; j < 4; ++j) oacc[0][n][j] *= alj[j];
        mrun0 = mn;
      }
      {
        float mn = fmaxf(mrun1, pm1);
        float al = __builtin_amdgcn_exp2f(mrun1 - mn);
        lrun1 *= al;
        float alj[4];
#pragma unroll
        for (int j = 0; j < 4; ++j) alj[j] = __shfl(al, 4 * lg + j);
#pragma unroll
        for (int n = 0; n < 4; ++n)
#pragma unroll
          for (int j = 0; j < 4; ++j) oacc[1][n][j] *= alj[j];
        mrun1 = mn;
      }
    }

    // fused exp + per-lane partial rowsum + pack, both groups
    float ps0 = 0.f, ps1 = 0.f;
#pragma unroll
    for (int n = 0; n < 4; ++n) {
      float v0 = __builtin_amdgcn_exp2f(s0[n][0] - mrun0);
      float v1 = __builtin_amdgcn_exp2f(s0[n][1] - mrun0);
      float v2 = __builtin_amdgcn_exp2f(s0[n][2] - mrun0);
      float v3 = __builtin_amdgcn_exp2f(s0[n][3] - mrun0);
      ps0 += (v0 + v1) + (v2 + v3);
      Pw0[lr * 32 + ((8 * n + 2 * lg) ^ xw)] = cvt_pk(v0, v1);
      Pw0[lr * 32 + ((8 * n + 2 * lg + 1) ^ xw)] = cvt_pk(v2, v3);
    }
#pragma unroll
    for (int n = 0; n < 4; ++n) {
      float v0 = __builtin_amdgcn_exp2f(s1[n][0] - mrun1);
      float v1 = __builtin_amdgcn_exp2f(s1[n][1] - mrun1);
      float v2 = __builtin_amdgcn_exp2f(s1[n][2] - mrun1);
      float v3 = __builtin_amdgcn_exp2f(s1[n][3] - mrun1);
      ps1 += (v0 + v1) + (v2 + v3);
      Pw1[lr * 32 + ((8 * n + 2 * lg) ^ xw)] = cvt_pk(v0, v1);
      Pw1[lr * 32 + ((8 * n + 2 * lg + 1) ^ xw)] = cvt_pk(v2, v3);
    }
    lrun0 += ps0;
    lrun1 += ps1;

    // PV: each vf read feeds 2 MFMAs (same-wave DS in-order after writes)
    __builtin_amdgcn_s_setprio(1);
#pragma unroll
    for (int kk = 0; kk < 2; ++kk) {
      bf16x8 pa0 = *(const bf16x8*)&Pw0[lr * 32 + ((16 * kk + 4 * lg) ^ xw)];
      bf16x8 pa1 = *(const bf16x8*)&Pw1[lr * 32 + ((16 * kk + 4 * lg) ^ xw)];
#pragma unroll
      for (int n = 0; n < 4; ++n) {
        bf16x8 vf = *(const bf16x8*)&Vts[bb][off[kk][n]];
        oacc[0][n] = __builtin_amdgcn_mfma_f32_16x16x32_bf16(pa0, vf, oacc[0][n], 0, 0, 0);
        oacc[1][n] = __builtin_amdgcn_mfma_f32_16x16x32_bf16(pa1, vf, oacc[1][n], 0, 0, 0);
      }
    }
    __builtin_amdgcn_s_setprio(0);
    RAWBAR();  // bounds skew; no drain needed (frags consumed)
  }
#undef ASTAGE

  // epilogue: finish l reductions, normalize, store 32 q-rows per wave
  lrun0 += __shfl_xor(lrun0, 16);
  lrun0 += __shfl_xor(lrun0, 32);
  lrun1 += __shfl_xor(lrun1, 16);
  lrun1 += __shfl_xor(lrun1, 32);
  float ri0 = __builtin_amdgcn_rcpf(lrun0);
  float ri1 = __builtin_amdgcn_rcpf(lrun1);
  float rj0[4], rj1[4];
#pragma unroll
  for (int j = 0; j < 4; ++j) {
    rj0[j] = __shfl(ri0, 4 * lg + j);
    rj1[j] = __shfl(ri1, 4 * lg + j);
  }
  int row0 = b * 2048 + q0 + w * 32 + lg * 4;
#pragma unroll
  for (int n = 0; n < 4; ++n) {
    int col = h * 64 + n * 16 + lr;
#pragma unroll
    for (int j = 0; j < 4; ++j) {
      hb[(size_t)(row0 + j) * 1024 + col] = f2bf(oacc[0][n][j] * rj0[j]);
      hb[(size_t)(row0 + 16 + j) * 1024 + col] = f2bf(oacc[1][n][j] * rj1[j]);
    }
  }
}

extern "C" void kernel_launch(void* const* d_in, const int* in_sizes, int n_in,
                              void* d_out, int out_size, void* d_ws,
                              size_t ws_size, hipStream_t stream) {
  const float* x = (const float*)d_in[0];
  const float* wq = (const float*)d_in[1];
  const float* wk = (const float*)d_in[2];
  const float* wv = (const float*)d_in[3];
  const float* wo = (const float*)d_in[4];

  u16* xb = (u16*)d_ws;              // [4096][1024]        4M
  u16* wqkv = xb + 4 * 1024 * 1024;  // [3072][1024]        3M
  u16* wot = wqkv + 3 * 1024 * 1024; // [1024][1024]        1M
  u16* qkb = wot + 1024 * 1024;      // [4096][2048] Q|K    8M
  u16* vtb = qkb + 8 * 1024 * 1024;  // [2][1024][2048] Vt  4M
  u16* hb = vtb + 4 * 1024 * 1024;   // [4096][1024] heads  4M

  cast_x<<<2048, 256, 0, stream>>>(x, xb);
  cast_wqkv<<<12288, 256, 0, stream>>>(wq, wk, wv, wqkv);
  cast_wo<<<4096, 256, 0, stream>>>(wo, wot);
  gemm_qkv<<<dim3(24, 16), 512, 0, stream>>>(xb, wqkv, qkb, vtb, 4096, 3072, 1024);
  attn<<<512, 256, 0, stream>>>(qkb, vtb, hb);
  gemm_out<<<dim3(8, 32), 256, 0, stream>>>(hb, wot, (float*)d_out, 4096, 1024, 1024);
}

// Round 9
// 127.329 us; speedup vs baseline: 1.3018x; 1.1137x over previous
//
#include <hip/hip_runtime.h>

typedef __attribute__((ext_vector_type(8))) short bf16x8;
typedef __attribute__((ext_vector_type(4))) float f32x4;
typedef __attribute__((ext_vector_type(4))) unsigned short u16x4;
typedef unsigned short u16;
typedef unsigned int u32;

static __device__ __forceinline__ u16 f2bf(float f) {
  u32 u = __float_as_uint(f);
  u32 r = (u + 0x7fffu + ((u >> 16) & 1u)) >> 16;  // RNE
  return (u16)r;
}

static __device__ __forceinline__ u32 cvt_pk(float lo, float hi) {
  u32 r;
  asm("v_cvt_pk_bf16_f32 %0, %1, %2" : "=v"(r) : "v"(lo), "v"(hi));
  return r;
}

#define GLDS16(g, l)                                                        \
  __builtin_amdgcn_global_load_lds(                                         \
      (const __attribute__((address_space(1))) u32*)(g),                    \
      (__attribute__((address_space(3))) u32*)(l), 16, 0, 0)

#define WAIT_VM3() asm volatile("s_waitcnt vmcnt(3)" ::: "memory")
#define WAIT_VM8() asm volatile("s_waitcnt vmcnt(8)" ::: "memory")
#define WAIT_VM0() asm volatile("s_waitcnt vmcnt(0)" ::: "memory")
#define RAWBAR() __builtin_amdgcn_s_barrier()

#define SC2F 0.18033688011112042f  // 0.125 * log2(e)

// ---------------- cast kernels ----------------
__global__ __launch_bounds__(256) void cast_x(const float* __restrict__ x,
                                              u16* __restrict__ xb) {
  int i = blockIdx.x * 256 + threadIdx.x;
  const float4* xv = (const float4*)x;
  float4 a = xv[i * 2], b = xv[i * 2 + 1];
  bf16x8 o;
  o[0] = f2bf(a.x); o[1] = f2bf(a.y); o[2] = f2bf(a.z); o[3] = f2bf(a.w);
  o[4] = f2bf(b.x); o[5] = f2bf(b.y); o[6] = f2bf(b.z); o[7] = f2bf(b.w);
  *(bf16x8*)(xb + i * 8) = o;
}

// LDS 64x64 transpose-cast: wt[n=sel*1024+h*64+kk][d] = W_sel[h][d][kk]
__global__ __launch_bounds__(256) void cast_wqkv(const float* __restrict__ wq,
                                                 const float* __restrict__ wk,
                                                 const float* __restrict__ wv,
                                                 u16* __restrict__ wt) {
  __shared__ u16 tile[64][66];
  int bid = blockIdx.x;  // 768 = sel(3) * h(16) * dt(16)
  int dt = bid & 15, h = (bid >> 4) & 15, sel = bid >> 8;
  const float* src = (sel == 0 ? wq : (sel == 1 ? wk : wv)) + h * 65536 + dt * 4096;
  int t = threadIdx.x;
  int r = t >> 4, c4 = (t & 15) * 4;
#pragma unroll
  for (int p = 0; p < 4; ++p) {
    int rr = r + p * 16;  // local d
    float4 v = *(const float4*)(src + rr * 64 + c4);  // coalesced
    u16x4 o;
    o[0] = f2bf(v.x); o[1] = f2bf(v.y); o[2] = f2bf(v.z); o[3] = f2bf(v.w);
    *(u16x4*)&tile[rr][c4] = o;  // tile[d][kk]
  }
  __syncthreads();
  int kk = t >> 3, dc = (t & 7) * 8;
  u16* dstb = wt + ((size_t)(sel * 1024 + h * 64)) * 1024 + dt * 64;
#pragma unroll
  for (int p = 0; p < 2; ++p) {
    int kkp = kk + p * 32;
    u16x4 a, b2;
#pragma unroll
    for (int i = 0; i < 4; ++i) {
      a[i] = tile[dc + i][kkp];
      b2[i] = tile[dc + 4 + i][kkp];
    }
    *(u16x4*)(dstb + (size_t)kkp * 1024 + dc) = a;
    *(u16x4*)(dstb + (size_t)kkp * 1024 + dc + 4) = b2;
  }
}

// LDS 64x64 transpose-cast: wt[n][k] = wo[k][n]
__global__ __launch_bounds__(256) void cast_wo(const float* __restrict__ wo,
                                               u16* __restrict__ wt) {
  __shared__ u16 tile[64][66];
  int bid = blockIdx.x;  // 256 = kt(16) * nt(16)
  int nt = bid & 15, kt = bid >> 4;
  const float* src = wo + (size_t)(kt * 64) * 1024 + nt * 64;
  int t = threadIdx.x;
  int r = t >> 4, c4 = (t & 15) * 4;
#pragma unroll
  for (int p = 0; p < 4; ++p) {
    int rr = r + p * 16;  // local k
    float4 v = *(const float4*)(src + (size_t)rr * 1024 + c4);
    u16x4 o;
    o[0] = f2bf(v.x); o[1] = f2bf(v.y); o[2] = f2bf(v.z); o[3] = f2bf(v.w);
    *(u16x4*)&tile[rr][c4] = o;  // tile[k][n]
  }
  __syncthreads();
  int nn = t >> 3, dc = (t & 7) * 8;
  u16* dstb = wt + (size_t)(nt * 64) * 1024 + kt * 64;
#pragma unroll
  for (int p = 0; p < 2; ++p) {
    int np = nn + p * 32;
    u16x4 a, b2;
#pragma unroll
    for (int i = 0; i < 4; ++i) {
      a[i] = tile[dc + i][np];
      b2[i] = tile[dc + 4 + i][np];
    }
    *(u16x4*)(dstb + (size_t)np * 1024 + dc) = a;
    *(u16x4*)(dstb + (size_t)np * 1024 + dc + 4) = b2;
  }
}

// ---------------- QKV GEMM: 256x128 tile, 512 threads, BK=32 -------------
// V-part blocks (n0>=2048) transpose the C-tile through LDS for coalesced
// b128 Vt writes (was 4KB-stride u16x4 scatter).
__global__ __launch_bounds__(512) void gemm_qkv(const u16* __restrict__ A,
                                                const u16* __restrict__ Bt,
                                                u16* __restrict__ qkb,
                                                u16* __restrict__ Vt, int M,
                                                int N, int K) {
  const int t = threadIdx.x;
  const int lane = t & 63, w = t >> 6;
  const int lr = lane & 15, lg = lane >> 4;
  const int wr = w >> 1, wc = w & 1;
  int lin = blockIdx.y * gridDim.x + blockIdx.x;
  int nwg = gridDim.x * gridDim.y;
  int swz = (lin & 7) * (nwg >> 3) + (lin >> 3);
  int bx = swz % gridDim.x, by = swz / gridDim.x;
  const int m0 = by * 256, n0 = bx * 128;
  __shared__ __align__(16) u16 SM[24576];  // As[2]:2*8192 | Bs[2]:2*4096
  const int ra = t >> 2, ca = (t & 3) * 8;
  const u16* a0 = A + (size_t)(m0 + ra) * K + ca;
  const u16* b0 = Bt + (size_t)(n0 + ra) * K + ca;
  const size_t ajmp = (size_t)128 * K;
  f32x4 acc[4][4] = {};

#define QSTAGE(bb, k0)                                       \
  {                                                          \
    GLDS16(a0 + (k0), &SM[(bb)*8192 + t * 8]);               \
    GLDS16(a0 + ajmp + (k0), &SM[(bb)*8192 + 4096 + t * 8]); \
    GLDS16(b0 + (k0), &SM[16384 + (bb)*4096 + t * 8]);       \
  }

  QSTAGE(0, 0);
  for (int k0 = 0; k0 < K; k0 += 32) {
    const int bb = (k0 >> 5) & 1;
    if (k0 + 32 < K) {
      QSTAGE(bb ^ 1, k0 + 32);
      WAIT_VM3();
    } else {
      WAIT_VM0();
    }
    RAWBAR();
    bf16x8 a[4], b[4];
#pragma unroll
    for (int m = 0; m < 4; ++m)
      a[m] = *(const bf16x8*)&SM[bb * 8192 + (wr * 64 + m * 16 + lr) * 32 + lg * 8];
#pragma unroll
    for (int n = 0; n < 4; ++n)
      b[n] = *(const bf16x8*)&SM[16384 + bb * 4096 + (wc * 64 + n * 16 + lr) * 32 + lg * 8];
    __builtin_amdgcn_s_setprio(1);
#pragma unroll
    for (int m = 0; m < 4; ++m)
#pragma unroll
      for (int n = 0; n < 4; ++n)
        acc[m][n] =
            __builtin_amdgcn_mfma_f32_16x16x32_bf16(a[m], b[n], acc[m][n], 0, 0, 0);
    __builtin_amdgcn_s_setprio(0);
    RAWBAR();
  }
#undef QSTAGE

  if (n0 < 2048) {  // Q | K: coalesced-ish u16 column stores
#pragma unroll
    for (int m = 0; m < 4; ++m) {
      int rowg = m0 + wr * 64 + m * 16 + lg * 4;
#pragma unroll
      for (int n = 0; n < 4; ++n) {
        int colg = n0 + wc * 64 + n * 16 + lr;
        float sc = colg < 1024 ? SC2F : 1.0f;  // fold softmax scale into Q
#pragma unroll
        for (int j = 0; j < 4; ++j)
          qkb[(size_t)(rowg + j) * 2048 + colg] = f2bf(acc[m][n][j] * sc);
      }
    }
  } else {  // V: transpose via LDS (VL[128][136] u16 = 34.8KB, fits in SM)
    const int bb2 = m0 >> 11, s0g = m0 & 2047;
    const int vbase = n0 - 2048;
#pragma unroll
    for (int c = 0; c < 2; ++c) {
      __syncthreads();
      if ((wr >> 1) == c) {
#pragma unroll
        for (int m = 0; m < 4; ++m)
#pragma unroll
          for (int n = 0; n < 4; ++n) {
            u16x4 pk;
#pragma unroll
            for (int j = 0; j < 4; ++j) pk[j] = f2bf(acc[m][n][j]);
            int vidx = wc * 64 + n * 16 + lr;
            int sl = (wr & 1) * 64 + m * 16 + lg * 4;
            *(u16x4*)&SM[vidx * 136 + sl] = pk;
          }
      }
      __syncthreads();
#pragma unroll
      for (int q = 0; q < 4; ++q) {
        int id = q * 512 + t;
        int vv = id >> 4, sc = id & 15;
        bf16x8 row = *(const bf16x8*)&SM[vv * 136 + sc * 8];
        *(bf16x8*)(Vt + ((size_t)(bb2 * 1024 + vbase + vv)) * 2048 + s0g +
                   c * 128 + sc * 8) = row;
      }
    }
  }
}

// ---------------- out-proj GEMM: 128x128 tile (f32 C) ---------------------
__global__ __launch_bounds__(256) void gemm_out(const u16* __restrict__ A,
                                                const u16* __restrict__ Bt,
                                                float* __restrict__ C, int M,
                                                int N, int K) {
  const int t = threadIdx.x;
  const int lane = t & 63, w = t >> 6;
  const int lr = lane & 15, lg = lane >> 4;
  const int wr = w >> 1, wc = w & 1;
  int lin = blockIdx.y * gridDim.x + blockIdx.x;
  int nwg = gridDim.x * gridDim.y;
  int swz = (lin & 7) * (nwg >> 3) + (lin >> 3);
  int bx = swz % gridDim.x, by = swz / gridDim.x;
  const int m0 = by * 128, n0 = bx * 128;
  __shared__ __align__(16) u16 As[2][128 * 32];
  __shared__ __align__(16) u16 Bs[2][128 * 32];
  const int r0 = t >> 2, cb = (t & 3) * 8;
  const u16* a0 = A + (size_t)(m0 + r0) * K + cb;
  const u16* b0 = Bt + (size_t)(n0 + r0) * K + cb;
  const size_t rowjmp = (size_t)64 * K;
  f32x4 acc[4][4] = {};

#define GSTAGE(bb, k0)                                      \
  {                                                         \
    GLDS16(a0 + (k0), &As[bb][t * 8]);                      \
    GLDS16(a0 + rowjmp + (k0), &As[bb][2048 + t * 8]);      \
    GLDS16(b0 + (k0), &Bs[bb][t * 8]);                      \
    GLDS16(b0 + rowjmp + (k0), &Bs[bb][2048 + t * 8]);      \
  }

  GSTAGE(0, 0);
  for (int k0 = 0; k0 < K; k0 += 32) {
    const int bb = (k0 >> 5) & 1;
    if (k0 + 32 < K) {
      GSTAGE(bb ^ 1, k0 + 32);
      asm volatile("s_waitcnt vmcnt(4)" ::: "memory");
    } else {
      WAIT_VM0();
    }
    RAWBAR();
    bf16x8 a[4], b[4];
#pragma unroll
    for (int m = 0; m < 4; ++m)
      a[m] = *(const bf16x8*)&As[bb][(wr * 64 + m * 16 + lr) * 32 + lg * 8];
#pragma unroll
    for (int n = 0; n < 4; ++n)
      b[n] = *(const bf16x8*)&Bs[bb][(wc * 64 + n * 16 + lr) * 32 + lg * 8];
    __builtin_amdgcn_s_setprio(1);
#pragma unroll
    for (int m = 0; m < 4; ++m)
#pragma unroll
      for (int n = 0; n < 4; ++n)
        acc[m][n] =
            __builtin_amdgcn_mfma_f32_16x16x32_bf16(a[m], b[n], acc[m][n], 0, 0, 0);
    __builtin_amdgcn_s_setprio(0);
    RAWBAR();
  }
#undef GSTAGE

#pragma unroll
  for (int m = 0; m < 4; ++m) {
    int rowg = m0 + wr * 64 + m * 16 + lg * 4;
#pragma unroll
    for (int n = 0; n < 4; ++n) {
      int colg = n0 + wc * 64 + n * 16 + lr;
#pragma unroll
      for (int j = 0; j < 4; ++j)
        C[(size_t)(rowg + j) * N + colg] = acc[m][n][j];
    }
  }
}

// ---------------- flash attention: QBLK=128, KVBLK=128 --------------------
// grid: 512 blocks = (b,h) * 16 q-tiles; 4 waves * 32 q-rows (2 groups).
// 16 KV tiles of 128: per-tile barrier/waitcnt overhead halved vs KVBLK=64.
// P staged in per-wave LDS in TWO sequential passes (k 0..63 then 64..127)
// reusing one 512-u32 buffer (same-wave DS is in-order => safe).
// LDS = 32K Ks-dbuf + 32K Vts-dbuf + 16K Ps = 80KB => 2 blocks/CU (= grid cap).
__global__ __launch_bounds__(256, 2) void attn(const u16* __restrict__ qkb,
                                               const u16* __restrict__ vtb,
                                               u16* __restrict__ hb) {
  const int t = threadIdx.x, lane = t & 63, w = t >> 6;
  const int lr = lane & 15, lg = lane >> 4;
  int lin = blockIdx.x;
  int swz2 = (lin & 7) * 64 + (lin >> 3);  // XCD locality
  int qi = swz2 & 15, bh = swz2 >> 4;
  int b = bh >> 4, h = bh & 15;
  int q0 = qi * 128;
  __shared__ __align__(16) u16 Ks[2][128 * 64];   // [s][dk], chunk^=(s&7)
  __shared__ __align__(16) u16 Vts[2][64 * 128];  // [dk][s], chunk^=(dk&15)
  __shared__ __align__(16) u32 Ps[4][2][512];     // per-wave/group P (64 k)

  bf16x8 qf[2][2];
#pragma unroll
  for (int g = 0; g < 2; ++g) {
    const u16* qb =
        qkb + (size_t)(b * 2048 + q0 + w * 32 + g * 16 + lr) * 2048 + h * 64;
    qf[g][0] = *(const bf16x8*)(qb + lg * 8);
    qf[g][1] = *(const bf16x8*)(qb + 32 + lg * 8);
  }

  f32x4 oacc[2][4] = {};
  float mrun0 = -1e30f, mrun1 = -1e30f;
  float lrun0 = 0.f, lrun1 = 0.f;

  // per-lane swizzled chunk offsets (u16 units)
  int chk[2], chv[4];
#pragma unroll
  for (int kk = 0; kk < 2; ++kk) chk[kk] = ((kk * 4 + lg) ^ (lr & 7)) * 8;
#pragma unroll
  for (int kk = 0; kk < 4; ++kk) chv[kk] = ((kk * 4 + lg) ^ lr) * 8;
  const int xw = (lr & 7) << 2;

  // staging: K 4 passes of 32 rows; V 4 passes of 16 rows
  const int rk = t >> 3, ck = t & 7;
  const int rv = t >> 4, cv = t & 15;
  const u16* Kg = qkb + (size_t)(b * 2048) * 2048 + 1024 + h * 64;
  const u16* Vg = vtb + (size_t)(b * 1024 + h * 64) * 2048;
  const u16* kp0 = Kg + (size_t)rk * 2048 + ((ck ^ (rk & 7)) * 8);
  const u16* vp0 = Vg + (size_t)rv * 2048 + ((cv ^ (rv & 15)) * 8);
  u32* Pw0 = &Ps[w][0][0];
  u32* Pw1 = &Ps[w][1][0];

#define ASTAGE(bb, tv)                                 \
  {                                                    \
    const u16* kp = kp0 + (size_t)(tv)*262144;         \
    const u16* vp = vp0 + (tv)*128;                    \
    GLDS16(kp, &Ks[bb][t * 8]);                        \
    GLDS16(kp + 65536, &Ks[bb][2048 + t * 8]);         \
    GLDS16(kp + 131072, &Ks[bb][4096 + t * 8]);        \
    GLDS16(kp + 196608, &Ks[bb][6144 + t * 8]);        \
    GLDS16(vp, &Vts[bb][t * 8]);                       \
    GLDS16(vp + 32768, &Vts[bb][2048 + t * 8]);        \
    GLDS16(vp + 65536, &Vts[bb][4096 + t * 8]);        \
    GLDS16(vp + 98304, &Vts[bb][6144 + t * 8]);        \
  }

  ASTAGE(0, 0);
  for (int tv = 0; tv < 16; ++tv) {
    const int bb = tv & 1;
    if (tv < 15) {
      ASTAGE(bb ^ 1, tv + 1);
      WAIT_VM8();
    } else {
      WAIT_VM0();
    }
    RAWBAR();

    // QK: S^T = K * Q^T, 8 fragment-cols (128 kv rows)
    f32x4 s0[8], s1[8];
#pragma unroll
    for (int n = 0; n < 8; ++n) {
      s0[n] = (f32x4){0.f, 0.f, 0.f, 0.f};
      s1[n] = (f32x4){0.f, 0.f, 0.f, 0.f};
    }
    __builtin_amdgcn_s_setprio(1);
#pragma unroll
    for (int kk = 0; kk < 2; ++kk)
#pragma unroll
      for (int n = 0; n < 8; ++n) {
        bf16x8 kf = *(const bf16x8*)&Ks[bb][n * 1024 + lr * 64 + chk[kk]];
        s0[n] = __builtin_amdgcn_mfma_f32_16x16x32_bf16(kf, qf[0][kk], s0[n], 0, 0, 0);
        s1[n] = __builtin_amdgcn_mfma_f32_16x16x32_bf16(kf, qf[1][kk], s1[n], 0, 0, 0);
      }
    __builtin_amdgcn_s_setprio(0);

    // row max over 32 in-lane values + 2 shuffles, per group
    float t0[8], t1[8];
#pragma unroll
    for (int n = 0; n < 8; ++n) {
      t0[n] = fmaxf(fmaxf(s0[n][0], s0[n][1]), fmaxf(s0[n][2], s0[n][3]));
      t1[n] = fmaxf(fmaxf(s1[n][0], s1[n][1]), fmaxf(s1[n][2], s1[n][3]));
    }
    float pm0 = fmaxf(fmaxf(fmaxf(t0[0], t0[1]), fmaxf(t0[2], t0[3])),
                      fmaxf(fmaxf(t0[4], t0[5]), fmaxf(t0[6], t0[7])));
    float pm1 = fmaxf(fmaxf(fmaxf(t1[0], t1[1]), fmaxf(t1[2], t1[3])),
                      fmaxf(fmaxf(t1[4], t1[5]), fmaxf(t1[6], t1[7])));
    pm0 = fmaxf(pm0, __shfl_xor(pm0, 16));
    pm0 = fmaxf(pm0, __shfl_xor(pm0, 32));
    pm1 = fmaxf(pm1, __shfl_xor(pm1, 16));
    pm1 = fmaxf(pm1, __shfl_xor(pm1, 32));

    if (__any(fmaxf(pm0 - mrun0, pm1 - mrun1) > 8.0f)) {  // T13 defer-max
      {
        float mn = fmaxf(mrun0, pm0);
        float al = __builtin_amdgcn_exp2f(mrun0 - mn);
        lrun0 *= al;
        float alj[4];
#pragma unroll
        for (int j = 0; j < 4; ++j) alj[j] = __shfl(al, 4 * lg + j);
#pragma unroll
        for (int n = 0; n < 4; ++n)
#pragma unroll
          for (int j = 0; j < 4; ++j) oacc[0][n][j] *= alj[j];
        mrun0 = mn;
      }
      {
        float mn = fmaxf(mrun1, pm1);
        float al = __builtin_amdgcn_exp2f(mrun1 - mn);
        lrun1 *= al;
        float alj[4];
#pragma unroll
        for (int j = 0; j < 4; ++j) alj[j] = __shfl(al, 4 * lg + j);
#pragma unroll
        for (int n = 0; n < 4; ++n)
#pragma unroll
          for (int j = 0; j < 4; ++j) oacc[1][n][j] *= alj[j];
        mrun1 = mn;
      }
    }

    float ps0 = 0.f, ps1 = 0.f;
    // ---- pass A: k 0..63 (n 0..3) ----
#pragma unroll
    for (int n = 0; n < 4; ++n) {
      float v0 = __builtin_amdgcn_exp2f(s0[n][0] - mrun0);
      float v1 = __builtin_amdgcn_exp2f(s0[n][1] - mrun0);
      float v2 = __builtin_amdgcn_exp2f(s0[n][2] - mrun0);
      float v3 = __builtin_amdgcn_exp2f(s0[n][3] - mrun0);
      ps0 += (v0 + v1) + (v2 + v3);
      Pw0[lr * 32 + ((8 * n + 2 * lg) ^ xw)] = cvt_pk(v0, v1);
      Pw0[lr * 32 + ((8 * n + 2 * lg + 1) ^ xw)] = cvt_pk(v2, v3);
      float u0 = __builtin_amdgcn_exp2f(s1[n][0] - mrun1);
      float u1 = __builtin_amdgcn_exp2f(s1[n][1] - mrun1);
      float u2 = __builtin_amdgcn_exp2f(s1[n][2] - mrun1);
      float u3 = __builtin_amdgcn_exp2f(s1[n][3] - mrun1);
      ps1 += (u0 + u1) + (u2 + u3);
      Pw1[lr * 32 + ((8 * n + 2 * lg) ^ xw)] = cvt_pk(u0, u1);
      Pw1[lr * 32 + ((8 * n + 2 * lg + 1) ^ xw)] = cvt_pk(u2, u3);
    }
    __builtin_amdgcn_s_setprio(1);
#pragma unroll
    for (int kk = 0; kk < 2; ++kk) {
      bf16x8 pa0 = *(const bf16x8*)&Pw0[lr * 32 + ((16 * kk + 4 * lg) ^ xw)];
      bf16x8 pa1 = *(const bf16x8*)&Pw1[lr * 32 + ((16 * kk + 4 * lg) ^ xw)];
#pragma unroll
      for (int n = 0; n < 4; ++n) {
        bf16x8 vf = *(const bf16x8*)&Vts[bb][n * 2048 + lr * 128 + chv[kk]];
        oacc[0][n] = __builtin_amdgcn_mfma_f32_16x16x32_bf16(pa0, vf, oacc[0][n], 0, 0, 0);
        oacc[1][n] = __builtin_amdgcn_mfma_f32_16x16x32_bf16(pa1, vf, oacc[1][n], 0, 0, 0);
      }
    }
    __builtin_amdgcn_s_setprio(0);
    // ---- pass B: k 64..127 (n 4..7), reuse Ps (same-wave DS in-order) ----
#pragma unroll
    for (int n = 4; n < 8; ++n) {
      float v0 = __builtin_amdgcn_exp2f(s0[n][0] - mrun0);
      float v1 = __builtin_amdgcn_exp2f(s0[n][1] - mrun0);
      float v2 = __builtin_amdgcn_exp2f(s0[n][2] - mrun0);
      float v3 = __builtin_amdgcn_exp2f(s0[n][3] - mrun0);
      ps0 += (v0 + v1) + (v2 + v3);
      Pw0[lr * 32 + ((8 * (n - 4) + 2 * lg) ^ xw)] = cvt_pk(v0, v1);
      Pw0[lr * 32 + ((8 * (n - 4) + 2 * lg + 1) ^ xw)] = cvt_pk(v2, v3);
      float u0 = __builtin_amdgcn_exp2f(s1[n][0] - mrun1);
      float u1 = __builtin_amdgcn_exp2f(s1[n][1] - mrun1);
      float u2 = __builtin_amdgcn_exp2f(s1[n][2] - mrun1);
      float u3 = __builtin_amdgcn_exp2f(s1[n][3] - mrun1);
      ps1 += (u0 + u1) + (u2 + u3);
      Pw1[lr * 32 + ((8 * (n - 4) + 2 * lg) ^ xw)] = cvt_pk(u0, u1);
      Pw1[lr * 32 + ((8 * (n - 4) + 2 * lg + 1) ^ xw)] = cvt_pk(u2, u3);
    }
    __builtin_amdgcn_s_setprio(1);
#pragma unroll
    for (int kk = 2; kk < 4; ++kk) {
      bf16x8 pa0 = *(const bf16x8*)&Pw0[lr * 32 + ((16 * (kk - 2) + 4 * lg) ^ xw)];
      bf16x8 pa1 = *(const bf16x8*)&Pw1[lr * 32 + ((16 * (kk - 2) + 4 * lg) ^ xw)];
#pragma unroll
      for (int n = 0; n < 4; ++n) {
        bf16x8 vf = *(const bf16x8*)&Vts[bb][n * 2048 + lr * 128 + chv[kk]];
        oacc[0][n] = __builtin_amdgcn_mfma_f32_16x16x32_bf16(pa0, vf, oacc[0][n], 0, 0, 0);
        oacc[1][n] = __builtin_amdgcn_mfma_f32_16x16x32_bf16(pa1, vf, oacc[1][n], 0, 0, 0);
      }
    }
    __builtin_amdgcn_s_setprio(0);
    lrun0 += ps0;
    lrun1 += ps1;
    RAWBAR();
  }
#undef ASTAGE

  lrun0 += __shfl_xor(lrun0, 16);
  lrun0 += __shfl_xor(lrun0, 32);
  lrun1 += __shfl_xor(lrun1, 16);
  lrun1 += __shfl_xor(lrun1, 32);
  float ri0 = __builtin_amdgcn_rcpf(lrun0);
  float ri1 = __builtin_amdgcn_rcpf(lrun1);
  float rj0[4], rj1[4];
#pragma unroll
  for (int j = 0; j < 4; ++j) {
    rj0[j] = __shfl(ri0, 4 * lg + j);
    rj1[j] = __shfl(ri1, 4 * lg + j);
  }
  int row0 = b * 2048 + q0 + w * 32 + lg * 4;
#pragma unroll
  for (int n = 0; n < 4; ++n) {
    int col = h * 64 + n * 16 + lr;
#pragma unroll
    for (int j = 0; j < 4; ++j) {
      hb[(size_t)(row0 + j) * 1024 + col] = f2bf(oacc[0][n][j] * rj0[j]);
      hb[(size_t)(row0 + 16 + j) * 1024 + col] = f2bf(oacc[1][n][j] * rj1[j]);
    }
  }
}

extern "C" void kernel_launch(void* const* d_in, const int* in_sizes, int n_in,
                              void* d_out, int out_size, void* d_ws,
                              size_t ws_size, hipStream_t stream) {
  const float* x = (const float*)d_in[0];
  const float* wq = (const float*)d_in[1];
  const float* wk = (const float*)d_in[2];
  const float* wv = (const float*)d_in[3];
  const float* wo = (const float*)d_in[4];

  u16* xb = (u16*)d_ws;              // [4096][1024]        4M
  u16* wqkv = xb + 4 * 1024 * 1024;  // [3072][1024]        3M
  u16* wot = wqkv + 3 * 1024 * 1024; // [1024][1024]        1M
  u16* qkb = wot + 1024 * 1024;      // [4096][2048] Q|K    8M
  u16* vtb = qkb + 8 * 1024 * 1024;  // [2][1024][2048] Vt  4M
  u16* hb = vtb + 4 * 1024 * 1024;   // [4096][1024] heads  4M

  cast_x<<<2048, 256, 0, stream>>>(x, xb);
  cast_wqkv<<<768, 256, 0, stream>>>(wq, wk, wv, wqkv);
  cast_wo<<<256, 256, 0, stream>>>(wo, wot);
  gemm_qkv<<<dim3(24, 16), 512, 0, stream>>>(xb, wqkv, qkb, vtb, 4096, 3072, 1024);
  attn<<<512, 256, 0, stream>>>(qkb, vtb, hb);
  gemm_out<<<dim3(8, 32), 256, 0, stream>>>(hb, wot, (float*)d_out, 4096, 1024, 1024);
}

// Round 10
// 123.324 us; speedup vs baseline: 1.3441x; 1.0325x over previous
//
#include <hip/hip_runtime.h>

typedef __attribute__((ext_vector_type(8))) short bf16x8;
typedef __attribute__((ext_vector_type(4))) float f32x4;
typedef __attribute__((ext_vector_type(4))) unsigned short u16x4;
typedef unsigned short u16;
typedef unsigned int u32;

static __device__ __forceinline__ u16 f2bf(float f) {
  u32 u = __float_as_uint(f);
  u32 r = (u + 0x7fffu + ((u >> 16) & 1u)) >> 16;  // RNE
  return (u16)r;
}

static __device__ __forceinline__ u32 cvt_pk(float lo, float hi) {
  u32 r;
  asm("v_cvt_pk_bf16_f32 %0, %1, %2" : "=v"(r) : "v"(lo), "v"(hi));
  return r;
}

#define GLDS16(g, l)                                                        \
  __builtin_amdgcn_global_load_lds(                                         \
      (const __attribute__((address_space(1))) u32*)(g),                    \
      (__attribute__((address_space(3))) u32*)(l), 16, 0, 0)

#define WAIT_VM5() asm volatile("s_waitcnt vmcnt(5)" ::: "memory")
#define WAIT_VM8() asm volatile("s_waitcnt vmcnt(8)" ::: "memory")
#define WAIT_VM4() asm volatile("s_waitcnt vmcnt(4)" ::: "memory")
#define WAIT_VM0() asm volatile("s_waitcnt vmcnt(0)" ::: "memory")
#define RAWBAR() __builtin_amdgcn_s_barrier()

#define SC2F 0.18033688011112042f  // 0.125 * log2(e)

// ---------------- fused cast kernel ----------------
// bid < 2048: cast x -> bf16 (1 thread / 8 elems)
// bid < 2816: wqkv transpose-cast, col layout n = h*192 + sel*64 + kk
// else      : wo transpose-cast wt[n][k] = wo[k][n]
__global__ __launch_bounds__(256) void cast_all(const float* __restrict__ x,
                                                const float* __restrict__ wq,
                                                const float* __restrict__ wk,
                                                const float* __restrict__ wv,
                                                const float* __restrict__ wo,
                                                u16* __restrict__ xb,
                                                u16* __restrict__ wqkv,
                                                u16* __restrict__ wot) {
  __shared__ u16 tile[64][66];
  int bid = blockIdx.x, t = threadIdx.x;
  if (bid < 2048) {
    int i = bid * 256 + t;
    const float4* xv = (const float4*)x;
    float4 a = xv[i * 2], b = xv[i * 2 + 1];
    bf16x8 o;
    o[0] = f2bf(a.x); o[1] = f2bf(a.y); o[2] = f2bf(a.z); o[3] = f2bf(a.w);
    o[4] = f2bf(b.x); o[5] = f2bf(b.y); o[6] = f2bf(b.z); o[7] = f2bf(b.w);
    *(bf16x8*)(xb + i * 8) = o;
    return;
  }
  const float* src;
  u16* dstb;
  if (bid < 2816) {
    int id = bid - 2048;  // 768 = sel(3) * h(16) * dt(16)
    int dt = id & 15, h = (id >> 4) & 15, sel = id >> 8;
    src = (sel == 0 ? wq : (sel == 1 ? wk : wv)) + h * 65536 + dt * 4096;
    dstb = wqkv + ((size_t)(h * 192 + sel * 64)) * 1024 + dt * 64;
    int r = t >> 4, c4 = (t & 15) * 4;
#pragma unroll
    for (int p = 0; p < 4; ++p) {
      int rr = r + p * 16;  // local d
      float4 v = *(const float4*)(src + rr * 64 + c4);
      u16x4 o;
      o[0] = f2bf(v.x); o[1] = f2bf(v.y); o[2] = f2bf(v.z); o[3] = f2bf(v.w);
      *(u16x4*)&tile[rr][c4] = o;  // tile[d][kk]
    }
  } else {
    int id = bid - 2816;  // 256 = kt(16) * nt(16)
    int nt = id & 15, kt = id >> 4;
    src = wo + (size_t)(kt * 64) * 1024 + nt * 64;
    dstb = wot + (size_t)(nt * 64) * 1024 + kt * 64;
    int r = t >> 4, c4 = (t & 15) * 4;
#pragma unroll
    for (int p = 0; p < 4; ++p) {
      int rr = r + p * 16;  // local k
      float4 v = *(const float4*)(src + (size_t)rr * 1024 + c4);
      u16x4 o;
      o[0] = f2bf(v.x); o[1] = f2bf(v.y); o[2] = f2bf(v.z); o[3] = f2bf(v.w);
      *(u16x4*)&tile[rr][c4] = o;
    }
  }
  __syncthreads();
  int nn = t >> 3, dc = (t & 7) * 8;
#pragma unroll
  for (int p = 0; p < 2; ++p) {
    int np = nn + p * 32;
    u16x4 a, b2;
#pragma unroll
    for (int i = 0; i < 4; ++i) {
      a[i] = tile[dc + i][np];
      b2[i] = tile[dc + 4 + i][np];
    }
    *(u16x4*)(dstb + (size_t)np * 1024 + dc) = a;
    *(u16x4*)(dstb + (size_t)np * 1024 + dc + 4) = b2;
  }
}

// ---------------- QKV GEMM: 128x192 tile, 256 threads, BK=32 -------------
// grid 16x32 = 512 = exactly 2 blocks/CU (no dispatch tail). Each N-tile is
// one head's [Q|K|V] column group (weight layout built by cast_all).
// V sub-block (cols 128..191) transposed through LDS for coalesced Vt rows.
__global__ __launch_bounds__(256) void gemm_qkv(const u16* __restrict__ A,
                                                const u16* __restrict__ Bt,
                                                u16* __restrict__ qkb,
                                                u16* __restrict__ Vt, int M,
                                                int N, int K) {
  const int t = threadIdx.x;
  const int lane = t & 63, w = t >> 6;
  const int lr = lane & 15, lg = lane >> 4;
  const int wr = w >> 1, wc = w & 1;  // 2M x 2N waves: 64 x 96 each
  int lin = blockIdx.y * gridDim.x + blockIdx.x;
  int nwg = gridDim.x * gridDim.y;
  int swz = (lin & 7) * (nwg >> 3) + (lin >> 3);
  int bx = swz % gridDim.x, by = swz / gridDim.x;
  const int m0 = by * 128, n0 = bx * 192, head = bx;
  __shared__ __align__(16) u16 SM[20480];  // As[2]@0 (2x4096) | Bs[2]@8192 (2x6144)
  const int ra = t >> 2, ca = (t & 3) * 8;
  const u16* a0 = A + (size_t)(m0 + ra) * K + ca;
  const u16* b0 = Bt + (size_t)(n0 + ra) * K + ca;
  f32x4 acc[4][6] = {};

#define QSTAGE(bb, k0)                                              \
  {                                                                 \
    GLDS16(a0 + (k0), &SM[(bb)*4096 + t * 8]);                      \
    GLDS16(a0 + (size_t)64 * K + (k0), &SM[(bb)*4096 + 2048 + t * 8]); \
    GLDS16(b0 + (k0), &SM[8192 + (bb)*6144 + t * 8]);               \
    GLDS16(b0 + (size_t)64 * K + (k0), &SM[8192 + (bb)*6144 + 2048 + t * 8]); \
    GLDS16(b0 + (size_t)128 * K + (k0), &SM[8192 + (bb)*6144 + 4096 + t * 8]); \
  }

  QSTAGE(0, 0);
  for (int k0 = 0; k0 < K; k0 += 32) {
    const int bb = (k0 >> 5) & 1;
    if (k0 + 32 < K) {
      QSTAGE(bb ^ 1, k0 + 32);
      WAIT_VM5();
    } else {
      WAIT_VM0();
    }
    RAWBAR();
    bf16x8 a[4], b[6];
#pragma unroll
    for (int m = 0; m < 4; ++m)
      a[m] = *(const bf16x8*)&SM[bb * 4096 + (wr * 64 + m * 16 + lr) * 32 + lg * 8];
#pragma unroll
    for (int n = 0; n < 6; ++n)
      b[n] = *(const bf16x8*)&SM[8192 + bb * 6144 + (wc * 96 + n * 16 + lr) * 32 + lg * 8];
    __builtin_amdgcn_s_setprio(1);
#pragma unroll
    for (int m = 0; m < 4; ++m)
#pragma unroll
      for (int n = 0; n < 6; ++n)
        acc[m][n] =
            __builtin_amdgcn_mfma_f32_16x16x32_bf16(a[m], b[n], acc[m][n], 0, 0, 0);
    __builtin_amdgcn_s_setprio(0);
    RAWBAR();
  }
#undef QSTAGE

  // Q / K columns: direct stores
#pragma unroll
  for (int m = 0; m < 4; ++m) {
    int rowg = m0 + wr * 64 + m * 16 + lg * 4;
#pragma unroll
    for (int n = 0; n < 6; ++n) {
      int cg = wc * 96 + n * 16 + lr;
      if (cg < 64) {  // Q (scaled)
        int col = head * 64 + cg;
#pragma unroll
        for (int j = 0; j < 4; ++j)
          qkb[(size_t)(rowg + j) * 2048 + col] = f2bf(acc[m][n][j] * SC2F);
      } else if (cg < 128) {  // K
        int col = 1024 + head * 64 + (cg - 64);
#pragma unroll
        for (int j = 0; j < 4; ++j)
          qkb[(size_t)(rowg + j) * 2048 + col] = f2bf(acc[m][n][j]);
      }
    }
  }
  // V columns (cg 128..191 => wc==1, n 2..5): LDS transpose, coalesced out
  __syncthreads();
  if (wc == 1) {
#pragma unroll
    for (int m = 0; m < 4; ++m)
#pragma unroll
      for (int n = 2; n < 6; ++n) {
        int v = (n - 2) * 16 + lr;          // 0..63
        int s = wr * 64 + m * 16 + lg * 4;  // 0..127
        u16x4 pk;
#pragma unroll
        for (int j = 0; j < 4; ++j) pk[j] = f2bf(acc[m][n][j]);
        *(u16x4*)&SM[v * 136 + s] = pk;
      }
  }
  __syncthreads();
  const int bb2 = m0 >> 11, s0g = m0 & 2047;
  u16* vdst = Vt + ((size_t)(bb2 * 1024 + head * 64)) * 2048 + s0g;
#pragma unroll
  for (int q = 0; q < 4; ++q) {
    int id = q * 256 + t;
    int v = id >> 4, sc = id & 15;
    bf16x8 row = *(const bf16x8*)&SM[v * 136 + sc * 8];
    *(bf16x8*)(vdst + (size_t)v * 2048 + sc * 8) = row;
  }
}

// ---------------- out-proj GEMM: 128x128 tile (f32 C) ---------------------
__global__ __launch_bounds__(256) void gemm_out(const u16* __restrict__ A,
                                                const u16* __restrict__ Bt,
                                                float* __restrict__ C, int M,
                                                int N, int K) {
  const int t = threadIdx.x;
  const int lane = t & 63, w = t >> 6;
  const int lr = lane & 15, lg = lane >> 4;
  const int wr = w >> 1, wc = w & 1;
  int lin = blockIdx.y * gridDim.x + blockIdx.x;
  int nwg = gridDim.x * gridDim.y;
  int swz = (lin & 7) * (nwg >> 3) + (lin >> 3);
  int bx = swz % gridDim.x, by = swz / gridDim.x;
  const int m0 = by * 128, n0 = bx * 128;
  __shared__ __align__(16) u16 As[2][128 * 32];
  __shared__ __align__(16) u16 Bs[2][128 * 32];
  const int r0 = t >> 2, cb = (t & 3) * 8;
  const u16* a0 = A + (size_t)(m0 + r0) * K + cb;
  const u16* b0 = Bt + (size_t)(n0 + r0) * K + cb;
  const size_t rowjmp = (size_t)64 * K;
  f32x4 acc[4][4] = {};

#define GSTAGE(bb, k0)                                      \
  {                                                         \
    GLDS16(a0 + (k0), &As[bb][t * 8]);                      \
    GLDS16(a0 + rowjmp + (k0), &As[bb][2048 + t * 8]);      \
    GLDS16(b0 + (k0), &Bs[bb][t * 8]);                      \
    GLDS16(b0 + rowjmp + (k0), &Bs[bb][2048 + t * 8]);      \
  }

  GSTAGE(0, 0);
  for (int k0 = 0; k0 < K; k0 += 32) {
    const int bb = (k0 >> 5) & 1;
    if (k0 + 32 < K) {
      GSTAGE(bb ^ 1, k0 + 32);
      WAIT_VM4();
    } else {
      WAIT_VM0();
    }
    RAWBAR();
    bf16x8 a[4], b[4];
#pragma unroll
    for (int m = 0; m < 4; ++m)
      a[m] = *(const bf16x8*)&As[bb][(wr * 64 + m * 16 + lr) * 32 + lg * 8];
#pragma unroll
    for (int n = 0; n < 4; ++n)
      b[n] = *(const bf16x8*)&Bs[bb][(wc * 64 + n * 16 + lr) * 32 + lg * 8];
    __builtin_amdgcn_s_setprio(1);
#pragma unroll
    for (int m = 0; m < 4; ++m)
#pragma unroll
      for (int n = 0; n < 4; ++n)
        acc[m][n] =
            __builtin_amdgcn_mfma_f32_16x16x32_bf16(a[m], b[n], acc[m][n], 0, 0, 0);
    __builtin_amdgcn_s_setprio(0);
    RAWBAR();
  }
#undef GSTAGE

#pragma unroll
  for (int m = 0; m < 4; ++m) {
    int rowg = m0 + wr * 64 + m * 16 + lg * 4;
#pragma unroll
    for (int n = 0; n < 4; ++n) {
      int colg = n0 + wc * 64 + n * 16 + lr;
#pragma unroll
      for (int j = 0; j < 4; ++j)
        C[(size_t)(rowg + j) * N + colg] = acc[m][n][j];
    }
  }
}

// ---------------- flash attention: QBLK=128, KVBLK=128 (unchanged R9) -----
__global__ __launch_bounds__(256, 2) void attn(const u16* __restrict__ qkb,
                                               const u16* __restrict__ vtb,
                                               u16* __restrict__ hb) {
  const int t = threadIdx.x, lane = t & 63, w = t >> 6;
  const int lr = lane & 15, lg = lane >> 4;
  int lin = blockIdx.x;
  int swz2 = (lin & 7) * 64 + (lin >> 3);  // XCD locality
  int qi = swz2 & 15, bh = swz2 >> 4;
  int b = bh >> 4, h = bh & 15;
  int q0 = qi * 128;
  __shared__ __align__(16) u16 Ks[2][128 * 64];   // [s][dk], chunk^=(s&7)
  __shared__ __align__(16) u16 Vts[2][64 * 128];  // [dk][s], chunk^=(dk&15)
  __shared__ __align__(16) u32 Ps[4][2][512];     // per-wave/group P (64 k)

  bf16x8 qf[2][2];
#pragma unroll
  for (int g = 0; g < 2; ++g) {
    const u16* qb =
        qkb + (size_t)(b * 2048 + q0 + w * 32 + g * 16 + lr) * 2048 + h * 64;
    qf[g][0] = *(const bf16x8*)(qb + lg * 8);
    qf[g][1] = *(const bf16x8*)(qb + 32 + lg * 8);
  }

  f32x4 oacc[2][4] = {};
  float mrun0 = -1e30f, mrun1 = -1e30f;
  float lrun0 = 0.f, lrun1 = 0.f;

  int chk[2], chv[4];
#pragma unroll
  for (int kk = 0; kk < 2; ++kk) chk[kk] = ((kk * 4 + lg) ^ (lr & 7)) * 8;
#pragma unroll
  for (int kk = 0; kk < 4; ++kk) chv[kk] = ((kk * 4 + lg) ^ lr) * 8;
  const int xw = (lr & 7) << 2;

  const int rk = t >> 3, ck = t & 7;
  const int rv = t >> 4, cv = t & 15;
  const u16* Kg = qkb + (size_t)(b * 2048) * 2048 + 1024 + h * 64;
  const u16* Vg = vtb + (size_t)(b * 1024 + h * 64) * 2048;
  const u16* kp0 = Kg + (size_t)rk * 2048 + ((ck ^ (rk & 7)) * 8);
  const u16* vp0 = Vg + (size_t)rv * 2048 + ((cv ^ (rv & 15)) * 8);
  u32* Pw0 = &Ps[w][0][0];
  u32* Pw1 = &Ps[w][1][0];

#define ASTAGE(bb, tv)                                 \
  {                                                    \
    const u16* kp = kp0 + (size_t)(tv)*262144;         \
    const u16* vp = vp0 + (tv)*128;                    \
    GLDS16(kp, &Ks[bb][t * 8]);                        \
    GLDS16(kp + 65536, &Ks[bb][2048 + t * 8]);         \
    GLDS16(kp + 131072, &Ks[bb][4096 + t * 8]);        \
    GLDS16(kp + 196608, &Ks[bb][6144 + t * 8]);        \
    GLDS16(vp, &Vts[bb][t * 8]);                       \
    GLDS16(vp + 32768, &Vts[bb][2048 + t * 8]);        \
    GLDS16(vp + 65536, &Vts[bb][4096 + t * 8]);        \
    GLDS16(vp + 98304, &Vts[bb][6144 + t * 8]);        \
  }

  ASTAGE(0, 0);
  for (int tv = 0; tv < 16; ++tv) {
    const int bb = tv & 1;
    if (tv < 15) {
      ASTAGE(bb ^ 1, tv + 1);
      WAIT_VM8();
    } else {
      WAIT_VM0();
    }
    RAWBAR();

    f32x4 s0[8], s1[8];
#pragma unroll
    for (int n = 0; n < 8; ++n) {
      s0[n] = (f32x4){0.f, 0.f, 0.f, 0.f};
      s1[n] = (f32x4){0.f, 0.f, 0.f, 0.f};
    }
    __builtin_amdgcn_s_setprio(1);
#pragma unroll
    for (int kk = 0; kk < 2; ++kk)
#pragma unroll
      for (int n = 0; n < 8; ++n) {
        bf16x8 kf = *(const bf16x8*)&Ks[bb][n * 1024 + lr * 64 + chk[kk]];
        s0[n] = __builtin_amdgcn_mfma_f32_16x16x32_bf16(kf, qf[0][kk], s0[n], 0, 0, 0);
        s1[n] = __builtin_amdgcn_mfma_f32_16x16x32_bf16(kf, qf[1][kk], s1[n], 0, 0, 0);
      }
    __builtin_amdgcn_s_setprio(0);

    float t0[8], t1[8];
#pragma unroll
    for (int n = 0; n < 8; ++n) {
      t0[n] = fmaxf(fmaxf(s0[n][0], s0[n][1]), fmaxf(s0[n][2], s0[n][3]));
      t1[n] = fmaxf(fmaxf(s1[n][0], s1[n][1]), fmaxf(s1[n][2], s1[n][3]));
    }
    float pm0 = fmaxf(fmaxf(fmaxf(t0[0], t0[1]), fmaxf(t0[2], t0[3])),
                      fmaxf(fmaxf(t0[4], t0[5]), fmaxf(t0[6], t0[7])));
    float pm1 = fmaxf(fmaxf(fmaxf(t1[0], t1[1]), fmaxf(t1[2], t1[3])),
                      fmaxf(fmaxf(t1[4], t1[5]), fmaxf(t1[6], t1[7])));
    pm0 = fmaxf(pm0, __shfl_xor(pm0, 16));
    pm0 = fmaxf(pm0, __shfl_xor(pm0, 32));
    pm1 = fmaxf(pm1, __shfl_xor(pm1, 16));
    pm1 = fmaxf(pm1, __shfl_xor(pm1, 32));

    if (__any(fmaxf(pm0 - mrun0, pm1 - mrun1) > 8.0f)) {  // T13 defer-max
      {
        float mn = fmaxf(mrun0, pm0);
        float al = __builtin_amdgcn_exp2f(mrun0 - mn);
        lrun0 *= al;
        float alj[4];
#pragma unroll
        for (int j = 0; j < 4; ++j) alj[j] = __shfl(al, 4 * lg + j);
#pragma unroll
        for (int n = 0; n < 4; ++n)
#pragma unroll
          for (int j = 0; j < 4; ++j) oacc[0][n][j] *= alj[j];
        mrun0 = mn;
      }
      {
        float mn = fmaxf(mrun1, pm1);
        float al = __builtin_amdgcn_exp2f(mrun1 - mn);
        lrun1 *= al;
        float alj[4];
#pragma unroll
        for (int j = 0; j < 4; ++j) alj[j] = __shfl(al, 4 * lg + j);
#pragma unroll
        for (int n = 0; n < 4; ++n)
#pragma unroll
          for (int j = 0; j < 4; ++j) oacc[1][n][j] *= alj[j];
        mrun1 = mn;
      }
    }

    float ps0 = 0.f, ps1 = 0.f;
#pragma unroll
    for (int n = 0; n < 4; ++n) {
      float v0 = __builtin_amdgcn_exp2f(s0[n][0] - mrun0);
      float v1 = __builtin_amdgcn_exp2f(s0[n][1] - mrun0);
      float v2 = __builtin_amdgcn_exp2f(s0[n][2] - mrun0);
      float v3 = __builtin_amdgcn_exp2f(s0[n][3] - mrun0);
      ps0 += (v0 + v1) + (v2 + v3);
      Pw0[lr * 32 + ((8 * n + 2 * lg) ^ xw)] = cvt_pk(v0, v1);
      Pw0[lr * 32 + ((8 * n + 2 * lg + 1) ^ xw)] = cvt_pk(v2, v3);
      float u0 = __builtin_amdgcn_exp2f(s1[n][0] - mrun1);
      float u1 = __builtin_amdgcn_exp2f(s1[n][1] - mrun1);
      float u2 = __builtin_amdgcn_exp2f(s1[n][2] - mrun1);
      float u3 = __builtin_amdgcn_exp2f(s1[n][3] - mrun1);
      ps1 += (u0 + u1) + (u2 + u3);
      Pw1[lr * 32 + ((8 * n + 2 * lg) ^ xw)] = cvt_pk(u0, u1);
      Pw1[lr * 32 + ((8 * n + 2 * lg + 1) ^ xw)] = cvt_pk(u2, u3);
    }
    __builtin_amdgcn_s_setprio(1);
#pragma unroll
    for (int kk = 0; kk < 2; ++kk) {
      bf16x8 pa0 = *(const bf16x8*)&Pw0[lr * 32 + ((16 * kk + 4 * lg) ^ xw)];
      bf16x8 pa1 = *(const bf16x8*)&Pw1[lr * 32 + ((16 * kk + 4 * lg) ^ xw)];
#pragma unroll
      for (int n = 0; n < 4; ++n) {
        bf16x8 vf = *(const bf16x8*)&Vts[bb][n * 2048 + lr * 128 + chv[kk]];
        oacc[0][n] = __builtin_amdgcn_mfma_f32_16x16x32_bf16(pa0, vf, oacc[0][n], 0, 0, 0);
        oacc[1][n] = __builtin_amdgcn_mfma_f32_16x16x32_bf16(pa1, vf, oacc[1][n], 0, 0, 0);
      }
    }
    __builtin_amdgcn_s_setprio(0);
#pragma unroll
    for (int n = 4; n < 8; ++n) {
      float v0 = __builtin_amdgcn_exp2f(s0[n][0] - mrun0);
      float v1 = __builtin_amdgcn_exp2f(s0[n][1] - mrun0);
      float v2 = __builtin_amdgcn_exp2f(s0[n][2] - mrun0);
      float v3 = __builtin_amdgcn_exp2f(s0[n][3] - mrun0);
      ps0 += (v0 + v1) + (v2 + v3);
      Pw0[lr * 32 + ((8 * (n - 4) + 2 * lg) ^ xw)] = cvt_pk(v0, v1);
      Pw0[lr * 32 + ((8 * (n - 4) + 2 * lg + 1) ^ xw)] = cvt_pk(v2, v3);
      float u0 = __builtin_amdgcn_exp2f(s1[n][0] - mrun1);
      float u1 = __builtin_amdgcn_exp2f(s1[n][1] - mrun1);
      float u2 = __builtin_amdgcn_exp2f(s1[n][2] - mrun1);
      float u3 = __builtin_amdgcn_exp2f(s1[n][3] - mrun1);
      ps1 += (u0 + u1) + (u2 + u3);
      Pw1[lr * 32 + ((8 * (n - 4) + 2 * lg) ^ xw)] = cvt_pk(u0, u1);
      Pw1[lr * 32 + ((8 * (n - 4) + 2 * lg + 1) ^ xw)] = cvt_pk(u2, u3);
    }
    __builtin_amdgcn_s_setprio(1);
#pragma unroll
    for (int kk = 2; kk < 4; ++kk) {
      bf16x8 pa0 = *(const bf16x8*)&Pw0[lr * 32 + ((16 * (kk - 2) + 4 * lg) ^ xw)];
      bf16x8 pa1 = *(const bf16x8*)&Pw1[lr * 32 + ((16 * (kk - 2) + 4 * lg) ^ xw)];
#pragma unroll
      for (int n = 0; n < 4; ++n) {
        bf16x8 vf = *(const bf16x8*)&Vts[bb][n * 2048 + lr * 128 + chv[kk]];
        oacc[0][n] = __builtin_amdgcn_mfma_f32_16x16x32_bf16(pa0, vf, oacc[0][n], 0, 0, 0);
        oacc[1][n] = __builtin_amdgcn_mfma_f32_16x16x32_bf16(pa1, vf, oacc[1][n], 0, 0, 0);
      }
    }
    __builtin_amdgcn_s_setprio(0);
    lrun0 += ps0;
    lrun1 += ps1;
    RAWBAR();
  }
#undef ASTAGE

  lrun0 += __shfl_xor(lrun0, 16);
  lrun0 += __shfl_xor(lrun0, 32);
  lrun1 += __shfl_xor(lrun1, 16);
  lrun1 += __shfl_xor(lrun1, 32);
  float ri0 = __builtin_amdgcn_rcpf(lrun0);
  float ri1 = __builtin_amdgcn_rcpf(lrun1);
  float rj0[4], rj1[4];
#pragma unroll
  for (int j = 0; j < 4; ++j) {
    rj0[j] = __shfl(ri0, 4 * lg + j);
    rj1[j] = __shfl(ri1, 4 * lg + j);
  }
  int row0 = b * 2048 + q0 + w * 32 + lg * 4;
#pragma unroll
  for (int n = 0; n < 4; ++n) {
    int col = h * 64 + n * 16 + lr;
#pragma unroll
    for (int j = 0; j < 4; ++j) {
      hb[(size_t)(row0 + j) * 1024 + col] = f2bf(oacc[0][n][j] * rj0[j]);
      hb[(size_t)(row0 + 16 + j) * 1024 + col] = f2bf(oacc[1][n][j] * rj1[j]);
    }
  }
}

extern "C" void kernel_launch(void* const* d_in, const int* in_sizes, int n_in,
                              void* d_out, int out_size, void* d_ws,
                              size_t ws_size, hipStream_t stream) {
  const float* x = (const float*)d_in[0];
  const float* wq = (const float*)d_in[1];
  const float* wk = (const float*)d_in[2];
  const float* wv = (const float*)d_in[3];
  const float* wo = (const float*)d_in[4];

  u16* xb = (u16*)d_ws;              // [4096][1024]        4M
  u16* wqkv = xb + 4 * 1024 * 1024;  // [3072][1024]        3M
  u16* wot = wqkv + 3 * 1024 * 1024; // [1024][1024]        1M
  u16* qkb = wot + 1024 * 1024;      // [4096][2048] Q|K    8M
  u16* vtb = qkb + 8 * 1024 * 1024;  // [2][1024][2048] Vt  4M
  u16* hb = vtb + 4 * 1024 * 1024;   // [4096][1024] heads  4M

  cast_all<<<3072, 256, 0, stream>>>(x, wq, wk, wv, wo, xb, wqkv, wot);
  gemm_qkv<<<dim3(16, 32), 256, 0, stream>>>(xb, wqkv, qkb, vtb, 4096, 3072, 1024);
  attn<<<512, 256, 0, stream>>>(qkb, vtb, hb);
  gemm_out<<<dim3(8, 32), 256, 0, stream>>>(hb, wot, (float*)d_out, 4096, 1024, 1024);
}

// Round 11
// 116.322 us; speedup vs baseline: 1.4250x; 1.0602x over previous
//
#include <hip/hip_runtime.h>

typedef __attribute__((ext_vector_type(8))) short bf16x8;
typedef __attribute__((ext_vector_type(4))) float f32x4;
typedef __attribute__((ext_vector_type(4))) unsigned short u16x4;
typedef unsigned short u16;
typedef unsigned int u32;

static __device__ __forceinline__ u16 f2bf(float f) {
  u32 u = __float_as_uint(f);
  u32 r = (u + 0x7fffu + ((u >> 16) & 1u)) >> 16;  // RNE
  return (u16)r;
}

static __device__ __forceinline__ u32 cvt_pk(float lo, float hi) {
  u32 r;
  asm("v_cvt_pk_bf16_f32 %0, %1, %2" : "=v"(r) : "v"(lo), "v"(hi));
  return r;
}

static __device__ __forceinline__ float max3(float a, float b, float c) {
  float r;
  asm("v_max3_f32 %0, %1, %2, %3" : "=v"(r) : "v"(a), "v"(b), "v"(c));
  return r;
}

#define GLDS16(g, l)                                                        \
  __builtin_amdgcn_global_load_lds(                                         \
      (const __attribute__((address_space(1))) u32*)(g),                    \
      (__attribute__((address_space(3))) u32*)(l), 16, 0, 0)

#define WAIT_VM5() asm volatile("s_waitcnt vmcnt(5)" ::: "memory")
#define WAIT_VM8() asm volatile("s_waitcnt vmcnt(8)" ::: "memory")
#define WAIT_VM3() asm volatile("s_waitcnt vmcnt(3)" ::: "memory")
#define WAIT_VM0() asm volatile("s_waitcnt vmcnt(0)" ::: "memory")
#define RAWBAR() __builtin_amdgcn_s_barrier()

#define SC2F 0.18033688011112042f  // 0.125 * log2(e)

// ---------------- fused cast kernel ----------------
__global__ __launch_bounds__(256) void cast_all(const float* __restrict__ x,
                                                const float* __restrict__ wq,
                                                const float* __restrict__ wk,
                                                const float* __restrict__ wv,
                                                const float* __restrict__ wo,
                                                u16* __restrict__ xb,
                                                u16* __restrict__ wqkv,
                                                u16* __restrict__ wot) {
  __shared__ u16 tile[64][66];
  int bid = blockIdx.x, t = threadIdx.x;
  if (bid < 2048) {
    int i = bid * 256 + t;
    const float4* xv = (const float4*)x;
    float4 a = xv[i * 2], b = xv[i * 2 + 1];
    bf16x8 o;
    o[0] = f2bf(a.x); o[1] = f2bf(a.y); o[2] = f2bf(a.z); o[3] = f2bf(a.w);
    o[4] = f2bf(b.x); o[5] = f2bf(b.y); o[6] = f2bf(b.z); o[7] = f2bf(b.w);
    *(bf16x8*)(xb + i * 8) = o;
    return;
  }
  const float* src;
  u16* dstb;
  if (bid < 2816) {
    int id = bid - 2048;  // 768 = sel(3) * h(16) * dt(16)
    int dt = id & 15, h = (id >> 4) & 15, sel = id >> 8;
    src = (sel == 0 ? wq : (sel == 1 ? wk : wv)) + h * 65536 + dt * 4096;
    dstb = wqkv + ((size_t)(h * 192 + sel * 64)) * 1024 + dt * 64;
    int r = t >> 4, c4 = (t & 15) * 4;
#pragma unroll
    for (int p = 0; p < 4; ++p) {
      int rr = r + p * 16;
      float4 v = *(const float4*)(src + rr * 64 + c4);
      u16x4 o;
      o[0] = f2bf(v.x); o[1] = f2bf(v.y); o[2] = f2bf(v.z); o[3] = f2bf(v.w);
      *(u16x4*)&tile[rr][c4] = o;  // tile[d][kk]
    }
  } else {
    int id = bid - 2816;  // 256 = kt(16) * nt(16)
    int nt = id & 15, kt = id >> 4;
    src = wo + (size_t)(kt * 64) * 1024 + nt * 64;
    dstb = wot + (size_t)(nt * 64) * 1024 + kt * 64;
    int r = t >> 4, c4 = (t & 15) * 4;
#pragma unroll
    for (int p = 0; p < 4; ++p) {
      int rr = r + p * 16;
      float4 v = *(const float4*)(src + (size_t)rr * 1024 + c4);
      u16x4 o;
      o[0] = f2bf(v.x); o[1] = f2bf(v.y); o[2] = f2bf(v.z); o[3] = f2bf(v.w);
      *(u16x4*)&tile[rr][c4] = o;
    }
  }
  __syncthreads();
  int nn = t >> 3, dc = (t & 7) * 8;
#pragma unroll
  for (int p = 0; p < 2; ++p) {
    int np = nn + p * 32;
    u16x4 a, b2;
#pragma unroll
    for (int i = 0; i < 4; ++i) {
      a[i] = tile[dc + i][np];
      b2[i] = tile[dc + 4 + i][np];
    }
    *(u16x4*)(dstb + (size_t)np * 1024 + dc) = a;
    *(u16x4*)(dstb + (size_t)np * 1024 + dc + 4) = b2;
  }
}

// ---------------- QKV GEMM: 128x192 tile, 256 threads, BK=32 -------------
__global__ __launch_bounds__(256) void gemm_qkv(const u16* __restrict__ A,
                                                const u16* __restrict__ Bt,
                                                u16* __restrict__ qkb,
                                                u16* __restrict__ Vt, int M,
                                                int N, int K) {
  const int t = threadIdx.x;
  const int lane = t & 63, w = t >> 6;
  const int lr = lane & 15, lg = lane >> 4;
  const int wr = w >> 1, wc = w & 1;
  int lin = blockIdx.y * gridDim.x + blockIdx.x;
  int nwg = gridDim.x * gridDim.y;
  int swz = (lin & 7) * (nwg >> 3) + (lin >> 3);
  int bx = swz % gridDim.x, by = swz / gridDim.x;
  const int m0 = by * 128, n0 = bx * 192, head = bx;
  __shared__ __align__(16) u16 SM[20480];
  const int ra = t >> 2, ca = (t & 3) * 8;
  const u16* a0 = A + (size_t)(m0 + ra) * K + ca;
  const u16* b0 = Bt + (size_t)(n0 + ra) * K + ca;
  f32x4 acc[4][6] = {};

#define QSTAGE(bb, k0)                                              \
  {                                                                 \
    GLDS16(a0 + (k0), &SM[(bb)*4096 + t * 8]);                      \
    GLDS16(a0 + (size_t)64 * K + (k0), &SM[(bb)*4096 + 2048 + t * 8]); \
    GLDS16(b0 + (k0), &SM[8192 + (bb)*6144 + t * 8]);               \
    GLDS16(b0 + (size_t)64 * K + (k0), &SM[8192 + (bb)*6144 + 2048 + t * 8]); \
    GLDS16(b0 + (size_t)128 * K + (k0), &SM[8192 + (bb)*6144 + 4096 + t * 8]); \
  }

  QSTAGE(0, 0);
  for (int k0 = 0; k0 < K; k0 += 32) {
    const int bb = (k0 >> 5) & 1;
    if (k0 + 32 < K) {
      QSTAGE(bb ^ 1, k0 + 32);
      WAIT_VM5();
    } else {
      WAIT_VM0();
    }
    RAWBAR();
    bf16x8 a[4], b[6];
#pragma unroll
    for (int m = 0; m < 4; ++m)
      a[m] = *(const bf16x8*)&SM[bb * 4096 + (wr * 64 + m * 16 + lr) * 32 + lg * 8];
#pragma unroll
    for (int n = 0; n < 6; ++n)
      b[n] = *(const bf16x8*)&SM[8192 + bb * 6144 + (wc * 96 + n * 16 + lr) * 32 + lg * 8];
    __builtin_amdgcn_s_setprio(1);
#pragma unroll
    for (int m = 0; m < 4; ++m)
#pragma unroll
      for (int n = 0; n < 6; ++n)
        acc[m][n] =
            __builtin_amdgcn_mfma_f32_16x16x32_bf16(a[m], b[n], acc[m][n], 0, 0, 0);
    __builtin_amdgcn_s_setprio(0);
    RAWBAR();
  }
#undef QSTAGE

#pragma unroll
  for (int m = 0; m < 4; ++m) {
    int rowg = m0 + wr * 64 + m * 16 + lg * 4;
#pragma unroll
    for (int n = 0; n < 6; ++n) {
      int cg = wc * 96 + n * 16 + lr;
      if (cg < 64) {  // Q (scaled)
        int col = head * 64 + cg;
#pragma unroll
        for (int j = 0; j < 4; ++j)
          qkb[(size_t)(rowg + j) * 2048 + col] = f2bf(acc[m][n][j] * SC2F);
      } else if (cg < 128) {  // K
        int col = 1024 + head * 64 + (cg - 64);
#pragma unroll
        for (int j = 0; j < 4; ++j)
          qkb[(size_t)(rowg + j) * 2048 + col] = f2bf(acc[m][n][j]);
      }
    }
  }
  __syncthreads();
  if (wc == 1) {
#pragma unroll
    for (int m = 0; m < 4; ++m)
#pragma unroll
      for (int n = 2; n < 6; ++n) {
        int v = (n - 2) * 16 + lr;
        int s = wr * 64 + m * 16 + lg * 4;
        u16x4 pk;
#pragma unroll
        for (int j = 0; j < 4; ++j) pk[j] = f2bf(acc[m][n][j]);
        *(u16x4*)&SM[v * 136 + s] = pk;
      }
  }
  __syncthreads();
  const int bb2 = m0 >> 11, s0g = m0 & 2047;
  u16* vdst = Vt + ((size_t)(bb2 * 1024 + head * 64)) * 2048 + s0g;
#pragma unroll
  for (int q = 0; q < 4; ++q) {
    int id = q * 256 + t;
    int v = id >> 4, sc = id & 15;
    bf16x8 row = *(const bf16x8*)&SM[v * 136 + sc * 8];
    *(bf16x8*)(vdst + (size_t)v * 2048 + sc * 8) = row;
  }
}

// ---------------- out-proj GEMM: 64x128 tile, 512 blocks = 2/CU ----------
__global__ __launch_bounds__(256) void gemm_out(const u16* __restrict__ A,
                                                const u16* __restrict__ Bt,
                                                float* __restrict__ C, int M,
                                                int N, int K) {
  const int t = threadIdx.x;
  const int lane = t & 63, w = t >> 6;
  const int lr = lane & 15, lg = lane >> 4;
  const int wr = w >> 1, wc = w & 1;  // 2m x 2n waves, each 32 x 64
  int lin = blockIdx.y * gridDim.x + blockIdx.x;
  int nwg = gridDim.x * gridDim.y;
  int swz = (lin & 7) * (nwg >> 3) + (lin >> 3);
  int bx = swz % gridDim.x, by = swz / gridDim.x;
  const int m0 = by * 64, n0 = bx * 128;
  __shared__ __align__(16) u16 As[2][64 * 32];
  __shared__ __align__(16) u16 Bs[2][128 * 32];
  const int r0 = t >> 2, cb = (t & 3) * 8;
  const u16* a0 = A + (size_t)(m0 + r0) * K + cb;
  const u16* b0 = Bt + (size_t)(n0 + r0) * K + cb;
  const size_t rowjmp = (size_t)64 * K;
  f32x4 acc[2][4] = {};

#define GSTAGE(bb, k0)                                      \
  {                                                         \
    GLDS16(a0 + (k0), &As[bb][t * 8]);                      \
    GLDS16(b0 + (k0), &Bs[bb][t * 8]);                      \
    GLDS16(b0 + rowjmp + (k0), &Bs[bb][2048 + t * 8]);      \
  }

  GSTAGE(0, 0);
  for (int k0 = 0; k0 < K; k0 += 32) {
    const int bb = (k0 >> 5) & 1;
    if (k0 + 32 < K) {
      GSTAGE(bb ^ 1, k0 + 32);
      WAIT_VM3();
    } else {
      WAIT_VM0();
    }
    RAWBAR();
    bf16x8 a[2], b[4];
#pragma unroll
    for (int m = 0; m < 2; ++m)
      a[m] = *(const bf16x8*)&As[bb][(wr * 32 + m * 16 + lr) * 32 + lg * 8];
#pragma unroll
    for (int n = 0; n < 4; ++n)
      b[n] = *(const bf16x8*)&Bs[bb][(wc * 64 + n * 16 + lr) * 32 + lg * 8];
    __builtin_amdgcn_s_setprio(1);
#pragma unroll
    for (int m = 0; m < 2; ++m)
#pragma unroll
      for (int n = 0; n < 4; ++n)
        acc[m][n] =
            __builtin_amdgcn_mfma_f32_16x16x32_bf16(a[m], b[n], acc[m][n], 0, 0, 0);
    __builtin_amdgcn_s_setprio(0);
    RAWBAR();
  }
#undef GSTAGE

#pragma unroll
  for (int m = 0; m < 2; ++m) {
    int rowg = m0 + wr * 32 + m * 16 + lg * 4;
#pragma unroll
    for (int n = 0; n < 4; ++n) {
      int colg = n0 + wc * 64 + n * 16 + lr;
#pragma unroll
      for (int j = 0; j < 4; ++j)
        C[(size_t)(rowg + j) * N + colg] = acc[m][n][j];
    }
  }
}

// ---------------- flash attention: QBLK=128, KVBLK=128, ones-column l -----
// l is tracked as an extra PV accumulator column (B = all-ones fragment):
// it rides the alpha-rescale with O and needs no VALU adds or epilogue
// cross-lane reduction.
__global__ __launch_bounds__(256, 2) void attn(const u16* __restrict__ qkb,
                                               const u16* __restrict__ vtb,
                                               u16* __restrict__ hb) {
  const int t = threadIdx.x, lane = t & 63, w = t >> 6;
  const int lr = lane & 15, lg = lane >> 4;
  int lin = blockIdx.x;
  int swz2 = (lin & 7) * 64 + (lin >> 3);  // XCD locality
  int qi = swz2 & 15, bh = swz2 >> 4;
  int b = bh >> 4, h = bh & 15;
  int q0 = qi * 128;
  __shared__ __align__(16) u16 Ks[2][128 * 64];
  __shared__ __align__(16) u16 Vts[2][64 * 128];
  __shared__ __align__(16) u32 Ps[4][2][512];

  bf16x8 qf[2][2];
#pragma unroll
  for (int g = 0; g < 2; ++g) {
    const u16* qb =
        qkb + (size_t)(b * 2048 + q0 + w * 32 + g * 16 + lr) * 2048 + h * 64;
    qf[g][0] = *(const bf16x8*)(qb + lg * 8);
    qf[g][1] = *(const bf16x8*)(qb + 32 + lg * 8);
  }
  bf16x8 ones;
#pragma unroll
  for (int i = 0; i < 8; ++i) ones[i] = (short)0x3F80;  // bf16 1.0

  f32x4 oacc[2][4] = {};
  f32x4 le0 = {}, le1 = {};  // softmax denominators (ones-column PV)
  float mrun0 = -1e30f, mrun1 = -1e30f;

  int chk[2], chv[4];
#pragma unroll
  for (int kk = 0; kk < 2; ++kk) chk[kk] = ((kk * 4 + lg) ^ (lr & 7)) * 8;
#pragma unroll
  for (int kk = 0; kk < 4; ++kk) chv[kk] = ((kk * 4 + lg) ^ lr) * 8;
  const int xw = (lr & 7) << 2;

  const int rk = t >> 3, ck = t & 7;
  const int rv = t >> 4, cv = t & 15;
  const u16* Kg = qkb + (size_t)(b * 2048) * 2048 + 1024 + h * 64;
  const u16* Vg = vtb + (size_t)(b * 1024 + h * 64) * 2048;
  const u16* kp0 = Kg + (size_t)rk * 2048 + ((ck ^ (rk & 7)) * 8);
  const u16* vp0 = Vg + (size_t)rv * 2048 + ((cv ^ (rv & 15)) * 8);
  u32* Pw0 = &Ps[w][0][0];
  u32* Pw1 = &Ps[w][1][0];

#define ASTAGE(bb, tv)                                 \
  {                                                    \
    const u16* kp = kp0 + (size_t)(tv)*262144;         \
    const u16* vp = vp0 + (tv)*128;                    \
    GLDS16(kp, &Ks[bb][t * 8]);                        \
    GLDS16(kp + 65536, &Ks[bb][2048 + t * 8]);         \
    GLDS16(kp + 131072, &Ks[bb][4096 + t * 8]);        \
    GLDS16(kp + 196608, &Ks[bb][6144 + t * 8]);        \
    GLDS16(vp, &Vts[bb][t * 8]);                       \
    GLDS16(vp + 32768, &Vts[bb][2048 + t * 8]);        \
    GLDS16(vp + 65536, &Vts[bb][4096 + t * 8]);        \
    GLDS16(vp + 98304, &Vts[bb][6144 + t * 8]);        \
  }

  ASTAGE(0, 0);
  for (int tv = 0; tv < 16; ++tv) {
    const int bb = tv & 1;
    if (tv < 15) {
      ASTAGE(bb ^ 1, tv + 1);
      WAIT_VM8();
    } else {
      WAIT_VM0();
    }
    RAWBAR();

    f32x4 s0[8], s1[8];
#pragma unroll
    for (int n = 0; n < 8; ++n) {
      s0[n] = (f32x4){0.f, 0.f, 0.f, 0.f};
      s1[n] = (f32x4){0.f, 0.f, 0.f, 0.f};
    }
    __builtin_amdgcn_s_setprio(1);
#pragma unroll
    for (int kk = 0; kk < 2; ++kk)
#pragma unroll
      for (int n = 0; n < 8; ++n) {
        bf16x8 kf = *(const bf16x8*)&Ks[bb][n * 1024 + lr * 64 + chk[kk]];
        s0[n] = __builtin_amdgcn_mfma_f32_16x16x32_bf16(kf, qf[0][kk], s0[n], 0, 0, 0);
        s1[n] = __builtin_amdgcn_mfma_f32_16x16x32_bf16(kf, qf[1][kk], s1[n], 0, 0, 0);
      }
    __builtin_amdgcn_s_setprio(0);

    // row max: max3 trees over 32 in-lane values + 2 shuffles per group
    float t0[8], t1[8];
#pragma unroll
    for (int n = 0; n < 8; ++n) {
      t0[n] = fmaxf(max3(s0[n][0], s0[n][1], s0[n][2]), s0[n][3]);
      t1[n] = fmaxf(max3(s1[n][0], s1[n][1], s1[n][2]), s1[n][3]);
    }
    float pm0 = fmaxf(max3(max3(t0[0], t0[1], t0[2]), t0[3], t0[4]),
                      max3(t0[5], t0[6], t0[7]));
    float pm1 = fmaxf(max3(max3(t1[0], t1[1], t1[2]), t1[3], t1[4]),
                      max3(t1[5], t1[6], t1[7]));
    pm0 = fmaxf(pm0, __shfl_xor(pm0, 16));
    pm0 = fmaxf(pm0, __shfl_xor(pm0, 32));
    pm1 = fmaxf(pm1, __shfl_xor(pm1, 16));
    pm1 = fmaxf(pm1, __shfl_xor(pm1, 32));

    if (__any(fmaxf(pm0 - mrun0, pm1 - mrun1) > 8.0f)) {  // T13 defer-max
      {
        float mn = fmaxf(mrun0, pm0);
        float al = __builtin_amdgcn_exp2f(mrun0 - mn);
        float alj[4];
#pragma unroll
        for (int j = 0; j < 4; ++j) alj[j] = __shfl(al, 4 * lg + j);
#pragma unroll
        for (int j = 0; j < 4; ++j) le0[j] *= alj[j];
#pragma unroll
        for (int n = 0; n < 4; ++n)
#pragma unroll
          for (int j = 0; j < 4; ++j) oacc[0][n][j] *= alj[j];
        mrun0 = mn;
      }
      {
        float mn = fmaxf(mrun1, pm1);
        float al = __builtin_amdgcn_exp2f(mrun1 - mn);
        float alj[4];
#pragma unroll
        for (int j = 0; j < 4; ++j) alj[j] = __shfl(al, 4 * lg + j);
#pragma unroll
        for (int j = 0; j < 4; ++j) le1[j] *= alj[j];
#pragma unroll
        for (int n = 0; n < 4; ++n)
#pragma unroll
          for (int j = 0; j < 4; ++j) oacc[1][n][j] *= alj[j];
        mrun1 = mn;
      }
    }

    // ---- pass A: k 0..63 ----
#pragma unroll
    for (int n = 0; n < 4; ++n) {
      float v0 = __builtin_amdgcn_exp2f(s0[n][0] - mrun0);
      float v1 = __builtin_amdgcn_exp2f(s0[n][1] - mrun0);
      float v2 = __builtin_amdgcn_exp2f(s0[n][2] - mrun0);
      float v3 = __builtin_amdgcn_exp2f(s0[n][3] - mrun0);
      Pw0[lr * 32 + ((8 * n + 2 * lg) ^ xw)] = cvt_pk(v0, v1);
      Pw0[lr * 32 + ((8 * n + 2 * lg + 1) ^ xw)] = cvt_pk(v2, v3);
      float u0 = __builtin_amdgcn_exp2f(s1[n][0] - mrun1);
      float u1 = __builtin_amdgcn_exp2f(s1[n][1] - mrun1);
      float u2 = __builtin_amdgcn_exp2f(s1[n][2] - mrun1);
      float u3 = __builtin_amdgcn_exp2f(s1[n][3] - mrun1);
      Pw1[lr * 32 + ((8 * n + 2 * lg) ^ xw)] = cvt_pk(u0, u1);
      Pw1[lr * 32 + ((8 * n + 2 * lg + 1) ^ xw)] = cvt_pk(u2, u3);
    }
    __builtin_amdgcn_s_setprio(1);
#pragma unroll
    for (int kk = 0; kk < 2; ++kk) {
      bf16x8 pa0 = *(const bf16x8*)&Pw0[lr * 32 + ((16 * kk + 4 * lg) ^ xw)];
      bf16x8 pa1 = *(const bf16x8*)&Pw1[lr * 32 + ((16 * kk + 4 * lg) ^ xw)];
      le0 = __builtin_amdgcn_mfma_f32_16x16x32_bf16(pa0, ones, le0, 0, 0, 0);
      le1 = __builtin_amdgcn_mfma_f32_16x16x32_bf16(pa1, ones, le1, 0, 0, 0);
#pragma unroll
      for (int n = 0; n < 4; ++n) {
        bf16x8 vf = *(const bf16x8*)&Vts[bb][n * 2048 + lr * 128 + chv[kk]];
        oacc[0][n] = __builtin_amdgcn_mfma_f32_16x16x32_bf16(pa0, vf, oacc[0][n], 0, 0, 0);
        oacc[1][n] = __builtin_amdgcn_mfma_f32_16x16x32_bf16(pa1, vf, oacc[1][n], 0, 0, 0);
      }
    }
    __builtin_amdgcn_s_setprio(0);
    // ---- pass B: k 64..127 (reuse Ps; same-wave DS in-order) ----
#pragma unroll
    for (int n = 4; n < 8; ++n) {
      float v0 = __builtin_amdgcn_exp2f(s0[n][0] - mrun0);
      float v1 = __builtin_amdgcn_exp2f(s0[n][1] - mrun0);
      float v2 = __builtin_amdgcn_exp2f(s0[n][2] - mrun0);
      float v3 = __builtin_amdgcn_exp2f(s0[n][3] - mrun0);
      Pw0[lr * 32 + ((8 * (n - 4) + 2 * lg) ^ xw)] = cvt_pk(v0, v1);
      Pw0[lr * 32 + ((8 * (n - 4) + 2 * lg + 1) ^ xw)] = cvt_pk(v2, v3);
      float u0 = __builtin_amdgcn_exp2f(s1[n][0] - mrun1);
      float u1 = __builtin_amdgcn_exp2f(s1[n][1] - mrun1);
      float u2 = __builtin_amdgcn_exp2f(s1[n][2] - mrun1);
      float u3 = __builtin_amdgcn_exp2f(s1[n][3] - mrun1);
      Pw1[lr * 32 + ((8 * (n - 4) + 2 * lg) ^ xw)] = cvt_pk(u0, u1);
      Pw1[lr * 32 + ((8 * (n - 4) + 2 * lg + 1) ^ xw)] = cvt_pk(u2, u3);
    }
    __builtin_amdgcn_s_setprio(1);
#pragma unroll
    for (int kk = 2; kk < 4; ++kk) {
      bf16x8 pa0 = *(const bf16x8*)&Pw0[lr * 32 + ((16 * (kk - 2) + 4 * lg) ^ xw)];
      bf16x8 pa1 = *(const bf16x8*)&Pw1[lr * 32 + ((16 * (kk - 2) + 4 * lg) ^ xw)];
      le0 = __builtin_amdgcn_mfma_f32_16x16x32_bf16(pa0, ones, le0, 0, 0, 0);
      le1 = __builtin_amdgcn_mfma_f32_16x16x32_bf16(pa1, ones, le1, 0, 0, 0);
#pragma unroll
      for (int n = 0; n < 4; ++n) {
        bf16x8 vf = *(const bf16x8*)&Vts[bb][n * 2048 + lr * 128 + chv[kk]];
        oacc[0][n] = __builtin_amdgcn_mfma_f32_16x16x32_bf16(pa0, vf, oacc[0][n], 0, 0, 0);
        oacc[1][n] = __builtin_amdgcn_mfma_f32_16x16x32_bf16(pa1, vf, oacc[1][n], 0, 0, 0);
      }
    }
    __builtin_amdgcn_s_setprio(0);
    RAWBAR();
  }
#undef ASTAGE

  // epilogue: per-lane rcp of the ones-column accumulators (no shuffles)
  float rj0[4], rj1[4];
#pragma unroll
  for (int j = 0; j < 4; ++j) {
    rj0[j] = __builtin_amdgcn_rcpf(le0[j]);
    rj1[j] = __builtin_amdgcn_rcpf(le1[j]);
  }
  int row0 = b * 2048 + q0 + w * 32 + lg * 4;
#pragma unroll
  for (int n = 0; n < 4; ++n) {
    int col = h * 64 + n * 16 + lr;
#pragma unroll
    for (int j = 0; j < 4; ++j) {
      hb[(size_t)(row0 + j) * 1024 + col] = f2bf(oacc[0][n][j] * rj0[j]);
      hb[(size_t)(row0 + 16 + j) * 1024 + col] = f2bf(oacc[1][n][j] * rj1[j]);
    }
  }
}

extern "C" void kernel_launch(void* const* d_in, const int* in_sizes, int n_in,
                              void* d_out, int out_size, void* d_ws,
                              size_t ws_size, hipStream_t stream) {
  const float* x = (const float*)d_in[0];
  const float* wq = (const float*)d_in[1];
  const float* wk = (const float*)d_in[2];
  const float* wv = (const float*)d_in[3];
  const float* wo = (const float*)d_in[4];

  u16* xb = (u16*)d_ws;              // [4096][1024]        4M
  u16* wqkv = xb + 4 * 1024 * 1024;  // [3072][1024]        3M
  u16* wot = wqkv + 3 * 1024 * 1024; // [1024][1024]        1M
  u16* qkb = wot + 1024 * 1024;      // [4096][2048] Q|K    8M
  u16* vtb = qkb + 8 * 1024 * 1024;  // [2][1024][2048] Vt  4M
  u16* hb = vtb + 4 * 1024 * 1024;   // [4096][1024] heads  4M

  cast_all<<<3072, 256, 0, stream>>>(x, wq, wk, wv, wo, xb, wqkv, wot);
  gemm_qkv<<<dim3(16, 32), 256, 0, stream>>>(xb, wqkv, qkb, vtb, 4096, 3072, 1024);
  attn<<<512, 256, 0, stream>>>(qkb, vtb, hb);
  gemm_out<<<dim3(8, 64), 256, 0, stream>>>(hb, wot, (float*)d_out, 4096, 1024, 1024);
}